// Round 14
// baseline (12217.982 us; speedup 1.0000x reference)
//
#include <hip/hip_runtime.h>

typedef unsigned short u16;
typedef __bf16 bf16x8 __attribute__((ext_vector_type(8)));
typedef float f32x4 __attribute__((ext_vector_type(4)));

#define N_NODES 100000
#define D 256
#define NLAYER 4
#define E2N 300000
#define E3N 200000
#define TGT 2000

__device__ __forceinline__ u16 f2b(float f) {
    union { float f; unsigned u; } v; v.f = f;
    unsigned r = v.u + 0x7FFFu + ((v.u >> 16) & 1u);
    return (u16)(r >> 16);
}
__device__ __forceinline__ float b2f(u16 u) {
    union { unsigned u; float f; } v; v.u = ((unsigned)u) << 16; return v.f;
}

// async global->LDS, 16B per lane (lds dest = uniform base + lane*16)
__device__ __forceinline__ void gload16(const void* g, void* l) {
    __builtin_amdgcn_global_load_lds(
        (const __attribute__((address_space(1))) void*)g,
        (__attribute__((address_space(3))) void*)l, 16, 0, 0);
}

// ---------------- embedding gather ----------------
__global__ __launch_bounds__(256)
void embed_kernel(const int* __restrict__ x, const float* __restrict__ emb,
                  u16* __restrict__ hb, int n) {
    int wid = threadIdx.x >> 6, lane = threadIdx.x & 63;
    int row = blockIdx.x * 4 + wid;
    if (row >= n) return;
    int v = x[row];
    float4 f = *(const float4*)(emb + v * D + lane * 4);
    ushort4 o; o.x = f2b(f.x); o.y = f2b(f.y); o.z = f2b(f.z); o.w = f2b(f.w);
    *(ushort4*)(hb + row * D + lane * 4) = o;
}

// ---------------- W_root (L,K,N) f32 -> Wr (L,N,K) bf16 ----------------
__global__ __launch_bounds__(256)
void convert_wt(const float* __restrict__ W, u16* __restrict__ Wt,
                int total, int K, int N) {
    int idx = blockIdx.x * 256 + threadIdx.x;
    if (idx >= total) return;
    int kk = idx % K;
    int rem = idx / K;
    int nn = rem % N;
    int l  = rem / N;
    Wt[idx] = f2b(W[(l * K + kk) * N + nn]);
}

// ---------------- W_eA (L, A*256, A*256) -> Wcat[((l*A+s)*A+t)][c][k] ----------------
__global__ __launch_bounds__(256)
void convert_cat(const float* __restrict__ W, u16* __restrict__ Wt,
                 int A, int total) {
    int idx = blockIdx.x * 256 + threadIdx.x;
    if (idx >= total) return;
    int k = idx & 255;
    int c = (idx >> 8) & 255;
    int r = idx >> 16;           // (l*A + s)*A + t
    int t = r % A; int ls = r / A; int s = ls % A; int l = ls / A;
    int AD = A * 256;
    Wt[idx] = f2b(W[(size_t)(l * AD + t * 256 + k) * AD + s * 256 + c]);
}

// ---------------- counting sort: CSR (rowptr + edge-id col array) per (type,slot) ------
#define NBINS 100000
#define NSEG 5
#define TOTENT 1200000
#define RPW (NBINS + 1)
#define NSTRIPE 16
#define SBINS (NBINS / NSTRIPE)      // 6250
#define BPT 7

__global__ __launch_bounds__(256)
void zero_counts(int* __restrict__ counts) {
    int i = blockIdx.x * 256 + threadIdx.x;
    if (i < NSEG * NBINS) counts[i] = 0;
}

__device__ __forceinline__ void decode_entry(int i, const int* e2, const int* e3,
                                             int& seg, int& key, int& e, int& is2) {
    if (i < 2 * E2N) {
        int s = i / E2N; e = i - s * E2N;
        seg = s; key = e2[s * E2N + e]; is2 = 1;
    } else {
        int j = i - 2 * E2N; int s = j / E3N; e = j - s * E3N;
        seg = 2 + s; key = e3[s * E3N + e]; is2 = 0;
    }
}

__global__ __launch_bounds__(256)
void hist_kernel(const int* __restrict__ e2, const int* __restrict__ e3,
                 int* __restrict__ counts) {
    int i = blockIdx.x * 256 + threadIdx.x;
    if (i >= TOTENT) return;
    int seg, key, e, is2;
    decode_entry(i, e2, e3, seg, key, e, is2);
    atomicAdd(counts + seg * NBINS + key, 1);
}

__global__ __launch_bounds__(1024)
void scanA(int* __restrict__ counts, int* __restrict__ aux) {
    __shared__ int ps[1024];
    int* base = counts + (blockIdx.x / NSTRIPE) * NBINS + (blockIdx.x % NSTRIPE) * SBINS;
    int t = threadIdx.x;
    int b = t * BPT, en = b + BPT; if (en > SBINS) en = SBINS; if (b > SBINS) b = SBINS;
    int s = 0;
    for (int i = b; i < en; ++i) s += base[i];
    ps[t] = s; __syncthreads();
    for (int off = 1; off < 1024; off <<= 1) {
        int v = ps[t];
        if (t >= off) v += ps[t - off];
        __syncthreads();
        ps[t] = v; __syncthreads();
    }
    int run = (t == 0) ? 0 : ps[t - 1];
    for (int i = b; i < en; ++i) { int c = base[i]; base[i] = run; run += c; }
    if (t == 1023) aux[blockIdx.x] = ps[1023];
}

__global__ __launch_bounds__(256)
void scanB(int* __restrict__ aux) {
    int seg = threadIdx.x;
    if (seg >= NSEG) return;
    int run = 0;
    for (int i = 0; i < NSTRIPE; ++i) {
        int c = aux[seg * NSTRIPE + i];
        aux[seg * NSTRIPE + i] = run; run += c;
    }
}

__global__ __launch_bounds__(1024)
void scanC(int* __restrict__ counts, const int* __restrict__ aux) {
    int off = aux[blockIdx.x];
    if (off == 0) return;
    int* base = counts + (blockIdx.x / NSTRIPE) * NBINS + (blockIdx.x % NSTRIPE) * SBINS;
    int t = threadIdx.x;
    int b = t * BPT, en = b + BPT; if (en > SBINS) en = SBINS; if (b > SBINS) b = SBINS;
    for (int i = b; i < en; ++i) base[i] += off;
}

__global__ __launch_bounds__(256)
void copy_rowptr(const int* __restrict__ counts, int* __restrict__ rp) {
    int i = blockIdx.x * 256 + threadIdx.x;
    if (i >= NSEG * RPW) return;
    int seg = i / RPW, k = i - seg * RPW;
    rp[i] = (k < NBINS) ? counts[seg * NBINS + k] : (seg < 2 ? E2N : E3N);
}

__global__ __launch_bounds__(256)
void scatter_kernel(const int* __restrict__ e2, const int* __restrict__ e3,
                    int* __restrict__ counts, int* __restrict__ sorted2,
                    int* __restrict__ sorted3) {
    int i = blockIdx.x * 256 + threadIdx.x;
    if (i >= TOTENT) return;
    int seg, key, e, is2;
    decode_entry(i, e2, e3, seg, key, e, is2);
    int pos = atomicAdd(counts + seg * NBINS + key, 1);
    if (is2) sorted2[seg * E2N + pos] = e;
    else     sorted3[(seg - 2) * E3N + pos] = e;
}

// ---------------- csrsrc[e] = src_ids[csr[e]] ----------------
// note: slice (s,t=s) doubles as csrdst for segment s.
__global__ __launch_bounds__(256)
void build_csrsrc(const int* __restrict__ src_ids, const int* __restrict__ csr,
                  int* __restrict__ out, int E) {
    int i = blockIdx.x * 256 + threadIdx.x;
    if (i >= E) return;
    out[i] = src_ids[csr[i]];
}

// ---------------- fused conv: edge-parallel LDS-atomic gather + GEMM + accumulate -----
// Block = 64 dst nodes x 256 out cols, 8 waves (each: output cols wid*32..+31).
// Per (s,t) phase:
//   t==s : A row = deg_s(node) * h[node]   (diagonal identity - no gather)
//   t!=s : edge-parallel gather, 2 column-halves: f32 LDS atomics (free 2-way banks),
//          then convert half into bf16 sA. Edges fully independent -> deep MLP.
// MFMA: A from sA (proven layout), B from global (L2-resident). One epilogue RMW.
template<int ARITY>
__global__ __launch_bounds__(512)
void fused_conv(const u16* __restrict__ hb, const int* __restrict__ csrsrc,
                const int* __restrict__ rp, const u16* __restrict__ Wl,
                float* __restrict__ agg, int E) {
    __shared__ __align__(16) float sAf[64 * 130];   // 33,280 B
    __shared__ __align__(16) u16  sA[64 * 264];     // 33,792 B  (total 67 KB -> 2 blk/CU)
    const int m0 = blockIdx.x * 64;
    const int tid = threadIdx.x;
    const int lane = tid & 63;
    const int wid = tid >> 6;          // 0..7
    const int wcol = wid * 32;
    const int mtop = (m0 + 64 < N_NODES) ? m0 + 64 : N_NODES;

    f32x4 acc[4][2];
#pragma unroll
    for (int i = 0; i < 4; ++i)
#pragma unroll
        for (int j = 0; j < 2; ++j)
            acc[i][j] = f32x4{0.f, 0.f, 0.f, 0.f};

#pragma unroll 1
    for (int s = 0; s < ARITY; ++s) {
        const int* rps = rp + s * RPW;
        const int eb0 = rps[m0];
        const int eb1 = rps[mtop];
        const int* cd = csrsrc + (size_t)(s * ARITY + s) * E;   // dst nodes of seg s
#pragma unroll 1
        for (int t = 0; t < ARITY; ++t) {
            if (t == s) {
                __syncthreads();   // prev MFMA done reading sA
#pragma unroll
                for (int r = 0; r < 8; ++r) {
                    int nl = wid * 8 + r;
                    int node = m0 + nl;
                    ushort4 o = {0, 0, 0, 0};
                    if (node < N_NODES) {
                        float dgf = (float)(rps[node + 1] - rps[node]);
                        ushort4 h = *(const ushort4*)(hb + (size_t)node * 256 + lane * 4);
                        o.x = f2b(dgf * b2f(h.x)); o.y = f2b(dgf * b2f(h.y));
                        o.z = f2b(dgf * b2f(h.z)); o.w = f2b(dgf * b2f(h.w));
                    }
                    *(ushort4*)(sA + nl * 264 + lane * 4) = o;
                }
                __syncthreads();
            } else {
                const int* cs = csrsrc + (size_t)(s * ARITY + t) * E;
#pragma unroll 1
                for (int half = 0; half < 2; ++half) {
                    __syncthreads();   // prev convert reads / prev MFMA (half 0) done
#pragma unroll 4
                    for (int i = tid; i < 64 * 130; i += 512) sAf[i] = 0.f;
                    __syncthreads();
                    const int cbase = half * 128;
#pragma unroll 2
                    for (int e = eb0 + wid; e < eb1; e += 8) {
                        int src = cs[e];
                        int r = cd[e] - m0;
                        float va = b2f(hb[(size_t)src * 256 + cbase + lane]);
                        float vb = b2f(hb[(size_t)src * 256 + cbase + 64 + lane]);
                        atomicAdd(&sAf[r * 130 + lane], va);
                        atomicAdd(&sAf[r * 130 + 64 + lane], vb);
                    }
                    __syncthreads();   // atomics done (also prev MFMA done for half 0)
#pragma unroll 4
                    for (int i = tid; i < 64 * 128; i += 512) {
                        int r = i >> 7, c = i & 127;
                        sA[r * 264 + cbase + c] = f2b(sAf[r * 130 + c]);
                    }
                }
                __syncthreads();   // sA ready
            }
            // ---- MFMA: A from LDS, B cols wcol..wcol+31 from global (L2) ----
            const u16* Bt = Wl + (size_t)(s * ARITY + t) * 65536;
#pragma unroll
            for (int k0 = 0; k0 < 256; k0 += 64) {
#pragma unroll
                for (int ks = 0; ks < 2; ++ks) {
                    const int koff = k0 + ks * 32 + (lane >> 4) * 8;
                    bf16x8 af[4], bf[2];
#pragma unroll
                    for (int mi = 0; mi < 4; ++mi)
                        af[mi] = *(const bf16x8*)(sA + (mi * 16 + (lane & 15)) * 264 + koff);
#pragma unroll
                    for (int ni = 0; ni < 2; ++ni)
                        bf[ni] = *(const bf16x8*)(Bt + (size_t)(wcol + ni * 16 + (lane & 15)) * 256 + koff);
#pragma unroll
                    for (int mi = 0; mi < 4; ++mi)
#pragma unroll
                        for (int ni = 0; ni < 2; ++ni)
                            acc[mi][ni] = __builtin_amdgcn_mfma_f32_16x16x32_bf16(
                                af[mi], bf[ni], acc[mi][ni], 0, 0, 0);
                }
            }
        }
    }

    // epilogue: one RMW for all s-slots (block-exclusive rows)
    const int colb = wcol + (lane & 15);
#pragma unroll
    for (int mi = 0; mi < 4; ++mi) {
        int mbase = m0 + mi * 16 + ((lane >> 4) << 2);
#pragma unroll
        for (int r = 0; r < 4; ++r) {
            int m = mbase + r;
            if (m < N_NODES) {
#pragma unroll
                for (int ni = 0; ni < 2; ++ni)
                    agg[(size_t)m * 256 + colb + ni * 16] += acc[mi][ni][r];
            }
        }
    }
}

// ---------------- root GEMM (m97-style, INIT): agg = hb @ Wr^T ----------------
__global__ __launch_bounds__(256)
void gemm128(const u16* __restrict__ A, const u16* __restrict__ B,
             float* __restrict__ aggr, int M) {
    __shared__ __align__(16) u16 sA[128 * 64];
    __shared__ __align__(16) u16 sB[128 * 64];
    const int bid = blockIdx.x;
    const int mt = bid >> 1;
    const int nt = bid & 1;
    const int m0 = mt * 128;
    const int n0 = nt * 128;
    const int tid = threadIdx.x;
    const int lane = tid & 63;
    const int wid = tid >> 6;
    const int wm = (wid >> 1) * 64;
    const int wn = (wid & 1) * 64;
    const int lrow8 = lane >> 3;
    const int lcol  = (lane & 7) * 8;

    f32x4 acc[4][4];
#pragma unroll
    for (int i = 0; i < 4; ++i)
#pragma unroll
        for (int j = 0; j < 4; ++j)
            acc[i][j] = f32x4{0.f, 0.f, 0.f, 0.f};

    for (int k0 = 0; k0 < 256; k0 += 64) {
        __syncthreads();
#pragma unroll
        for (int i = 0; i < 4; ++i) {
            int row = wid * 32 + i * 8;
            int ar = m0 + row + lrow8; ar = (ar < M) ? ar : (M - 1);
            gload16(A + (size_t)ar * 256 + k0 + lcol, sA + row * 64);
            gload16(B + (size_t)(n0 + row + lrow8) * 256 + k0 + lcol, sB + row * 64);
        }
        __syncthreads();
#pragma unroll
        for (int ks = 0; ks < 2; ++ks) {
            const int koff = ks * 32 + (lane >> 4) * 8;
            bf16x8 af[4], bf[4];
#pragma unroll
            for (int mi = 0; mi < 4; ++mi)
                af[mi] = *(const bf16x8*)(sA + (wm + mi * 16 + (lane & 15)) * 64 + koff);
#pragma unroll
            for (int ni = 0; ni < 4; ++ni)
                bf[ni] = *(const bf16x8*)(sB + (wn + ni * 16 + (lane & 15)) * 64 + koff);
#pragma unroll
            for (int mi = 0; mi < 4; ++mi)
#pragma unroll
                for (int ni = 0; ni < 4; ++ni)
                    acc[mi][ni] = __builtin_amdgcn_mfma_f32_16x16x32_bf16(
                        af[mi], bf[ni], acc[mi][ni], 0, 0, 0);
        }
    }

    const int colb = n0 + wn + (lane & 15);
#pragma unroll
    for (int mi = 0; mi < 4; ++mi) {
        int mbase = m0 + wm + mi * 16 + ((lane >> 4) << 2);
#pragma unroll
        for (int r = 0; r < 4; ++r) {
            int m = mbase + r;
            if (m < M) {
#pragma unroll
                for (int ni = 0; ni < 4; ++ni)
                    aggr[(size_t)m * 256 + colb + ni * 16] = acc[mi][ni][r];
            }
        }
    }
}

// ---------------- h = LN(relu(agg)) -> bf16 ----------------
__global__ __launch_bounds__(256)
void relu_ln_kernel(const float* __restrict__ agg, const float* __restrict__ g,
                    const float* __restrict__ b, u16* __restrict__ hb, int n) {
    int wid = threadIdx.x >> 6, lane = threadIdx.x & 63;
    int row = blockIdx.x * 4 + wid;
    if (row >= n) return;
    float4 v = *(const float4*)(agg + row * D + lane * 4);
    v.x = fmaxf(v.x, 0.f); v.y = fmaxf(v.y, 0.f);
    v.z = fmaxf(v.z, 0.f); v.w = fmaxf(v.w, 0.f);
    float s  = v.x + v.y + v.z + v.w;
    float s2 = v.x * v.x + v.y * v.y + v.z * v.z + v.w * v.w;
#pragma unroll
    for (int off = 1; off < 64; off <<= 1) {
        s  += __shfl_xor(s, off);
        s2 += __shfl_xor(s2, off);
    }
    float mu = s * 0.00390625f;
    float var = s2 * 0.00390625f - mu * mu;
    float rs = rsqrtf(var + 1e-5f);
    float4 gg = *(const float4*)(g + lane * 4);
    float4 bb = *(const float4*)(b + lane * 4);
    ushort4 o;
    o.x = f2b((v.x - mu) * rs * gg.x + bb.x);
    o.y = f2b((v.y - mu) * rs * gg.y + bb.y);
    o.z = f2b((v.z - mu) * rs * gg.z + bb.z);
    o.w = f2b((v.w - mu) * rs * gg.w + bb.w);
    *(ushort4*)(hb + row * D + lane * 4) = o;
}

// ---------------- head layers ----------------
__global__ __launch_bounds__(256)
void head_layer(const u16* __restrict__ hb, const int* __restrict__ tgt,
                const float* __restrict__ inf,
                const float* __restrict__ W, const float* __restrict__ bias,
                const float* __restrict__ g, const float* __restrict__ beta,
                float* __restrict__ out, int gather) {
    __shared__ float xr[256];
    __shared__ float sm1[4], sm2[4];
    int t = blockIdx.x, tid = threadIdx.x;
    if (gather) { int node = tgt[t]; xr[tid] = b2f(hb[node * D + tid]); }
    else        { xr[tid] = inf[t * D + tid]; }
    __syncthreads();
    float a = bias[tid];
#pragma unroll 8
    for (int k = 0; k < 256; ++k) a = fmaf(xr[k], W[k * 256 + tid], a);
    float s = a, s2 = a * a;
#pragma unroll
    for (int off = 1; off < 64; off <<= 1) {
        s  += __shfl_xor(s, off);
        s2 += __shfl_xor(s2, off);
    }
    int wid = tid >> 6, lane = tid & 63;
    if (lane == 0) { sm1[wid] = s; sm2[wid] = s2; }
    __syncthreads();
    s  = sm1[0] + sm1[1] + sm1[2] + sm1[3];
    s2 = sm2[0] + sm2[1] + sm2[2] + sm2[3];
    float mu = s * 0.00390625f;
    float var = s2 * 0.00390625f - mu * mu;
    float rs = rsqrtf(var + 1e-5f);
    float y = (a - mu) * rs * g[tid] + beta[tid];
    out[t * 256 + tid] = fmaxf(y, 0.f);
}

__global__ __launch_bounds__(256)
void head_out(const float* __restrict__ in, const float* __restrict__ ow,
              const float* __restrict__ ob, float* __restrict__ out, int T) {
    int wid = threadIdx.x >> 6, lane = threadIdx.x & 63;
    int t = blockIdx.x * 4 + wid;
    if (t >= T) return;
    float4 v = *(const float4*)(in + t * D + lane * 4);
    float4 w = *(const float4*)(ow + lane * 4);
    float s = v.x * w.x + v.y * w.y + v.z * w.z + v.w * w.w;
#pragma unroll
    for (int off = 1; off < 64; off <<= 1) s += __shfl_xor(s, off);
    if (lane == 0) out[t] = s + ob[0];
}

extern "C" void kernel_launch(void* const* d_in, const int* in_sizes, int n_in,
                              void* d_out, int out_size, void* d_ws, size_t ws_size,
                              hipStream_t stream) {
    (void)in_sizes; (void)n_in; (void)out_size; (void)ws_size;
    const int*   x      = (const int*)d_in[0];
    const int*   e2     = (const int*)d_in[2];
    const int*   e3     = (const int*)d_in[3];
    const int*   tgt    = (const int*)d_in[4];
    const float* emb    = (const float*)d_in[5];
    const float* W_root = (const float*)d_in[6];
    const float* W_e2   = (const float*)d_in[7];
    const float* W_e3   = (const float*)d_in[8];
    const float* ln_g   = (const float*)d_in[9];
    const float* ln_b   = (const float*)d_in[10];
    const float* reg_W  = (const float*)d_in[11];
    const float* reg_b  = (const float*)d_in[12];
    const float* rln_g  = (const float*)d_in[13];
    const float* rln_b  = (const float*)d_in[14];
    const float* out_W  = (const float*)d_in[15];
    const float* out_b  = (const float*)d_in[16];
    float* out = (float*)d_out;

    // workspace layout — top 183,837,184 B (round-11/12/13-proven)
    char* ws = (char*)d_ws;
    float* agg     = (float*)(ws);                    // 102,400,000 B
    int*   counts  = (int*)  (ws);                    // aliases agg (dead until layer 0)
    u16*   hb      = (u16*)  (ws + 102400000);        //  51,200,000
    u16*   Wr      = (u16*)  (ws + 153600000);        //     524,288
    u16*   W2c     = (u16*)  (ws + 154124288);        //   2,097,152
    u16*   W3c     = (u16*)  (ws + 156221440);        //   4,718,592
    int*   sorted2 = (int*)  (ws + 160940032);        //   2,400,000
    int*   sorted3 = (int*)  (ws + 163340032);        //   2,400,000
    int*   rp      = (int*)  (ws + 165740032);        //   2,000,020 -> pad 2,000,128
    int*   aux     = (int*)  (ws + 167740160);        //         320 -> pad 1,024
    int*   csrsrc2 = (int*)  (ws + 167741184);        //   4,800,000 (2s x 2t x E2N)
    int*   csrsrc3 = (int*)  (ws + 172541184);        //   7,200,000 (3s x 3t x E3N)
    float* t0      = (float*)(ws + 179741184);        //   2,048,000
    float* t1      = (float*)(ws + 181789184);        //   2,048,000

    embed_kernel<<<N_NODES / 4, 256, 0, stream>>>(x, emb, hb, N_NODES);
    convert_wt<<<(NLAYER * 256 * 256 + 255) / 256, 256, 0, stream>>>(W_root, Wr, NLAYER * 256 * 256, 256, 256);
    convert_cat<<<(NLAYER * 4 * 65536 + 255) / 256, 256, 0, stream>>>(W_e2, W2c, 2, NLAYER * 4 * 65536);
    convert_cat<<<(NLAYER * 9 * 65536 + 255) / 256, 256, 0, stream>>>(W_e3, W3c, 3, NLAYER * 9 * 65536);

    zero_counts<<<(NSEG * NBINS + 255) / 256, 256, 0, stream>>>(counts);
    hist_kernel<<<(TOTENT + 255) / 256, 256, 0, stream>>>(e2, e3, counts);
    scanA<<<NSEG * NSTRIPE, 1024, 0, stream>>>(counts, aux);
    scanB<<<1, 256, 0, stream>>>(aux);
    scanC<<<NSEG * NSTRIPE, 1024, 0, stream>>>(counts, aux);
    copy_rowptr<<<(NSEG * RPW + 255) / 256, 256, 0, stream>>>(counts, rp);
    scatter_kernel<<<(TOTENT + 255) / 256, 256, 0, stream>>>(e2, e3, counts, sorted2, sorted3);

    for (int s = 0; s < 2; ++s)
        for (int t = 0; t < 2; ++t)
            build_csrsrc<<<(E2N + 255) / 256, 256, 0, stream>>>(
                e2 + (size_t)t * E2N, sorted2 + (size_t)s * E2N,
                csrsrc2 + (size_t)(s * 2 + t) * E2N, E2N);
    for (int s = 0; s < 3; ++s)
        for (int t = 0; t < 3; ++t)
            build_csrsrc<<<(E3N + 255) / 256, 256, 0, stream>>>(
                e3 + (size_t)t * E3N, sorted3 + (size_t)s * E3N,
                csrsrc3 + (size_t)(s * 3 + t) * E3N, E3N);

    const int mgrid = ((N_NODES + 127) / 128) * 2;   // 1564 (root)
    const int fgrid = (N_NODES + 63) / 64;           // 1563 (fused conv)

    for (int l = 0; l < NLAYER; ++l) {
        gemm128<<<mgrid, 256, 0, stream>>>(hb, Wr + (size_t)l * 65536, agg, N_NODES);
        fused_conv<2><<<fgrid, 512, 0, stream>>>(
            hb, csrsrc2, rp, W2c + (size_t)l * 4 * 65536, agg, E2N);
        fused_conv<3><<<fgrid, 512, 0, stream>>>(
            hb, csrsrc3, rp + 2 * RPW, W3c + (size_t)l * 9 * 65536, agg, E3N);
        relu_ln_kernel<<<N_NODES / 4, 256, 0, stream>>>(agg, ln_g + l * D, ln_b + l * D, hb, N_NODES);
    }

    head_layer<<<TGT, 256, 0, stream>>>(hb, tgt, nullptr, reg_W, reg_b, rln_g, rln_b, t0, 1);
    head_layer<<<TGT, 256, 0, stream>>>(nullptr, nullptr, t0, reg_W + 65536, reg_b + 256, rln_g + 256, rln_b + 256, t1, 0);
    head_out<<<(TGT + 3) / 4, 256, 0, stream>>>(t1, out_W, out_b, out, TGT);
}

// Round 15
// 3653.917 us; speedup vs baseline: 3.3438x; 3.3438x over previous
//
#include <hip/hip_runtime.h>

typedef unsigned short u16;
typedef __bf16 bf16x8 __attribute__((ext_vector_type(8)));
typedef float f32x4 __attribute__((ext_vector_type(4)));

#define N_NODES 100000
#define D 256
#define NLAYER 4
#define E2N 300000
#define E3N 200000
#define TGT 2000

__device__ __forceinline__ u16 f2b(float f) {
    union { float f; unsigned u; } v; v.f = f;
    unsigned r = v.u + 0x7FFFu + ((v.u >> 16) & 1u);
    return (u16)(r >> 16);
}
__device__ __forceinline__ float b2f(u16 u) {
    union { unsigned u; float f; } v; v.u = ((unsigned)u) << 16; return v.f;
}

// async global->LDS, 16B per lane (lds dest = uniform base + lane*16)
__device__ __forceinline__ void gload16(const void* g, void* l) {
    __builtin_amdgcn_global_load_lds(
        (const __attribute__((address_space(1))) void*)g,
        (__attribute__((address_space(3))) void*)l, 16, 0, 0);
}

// ---------------- embedding gather ----------------
__global__ __launch_bounds__(256)
void embed_kernel(const int* __restrict__ x, const float* __restrict__ emb,
                  u16* __restrict__ hb, int n) {
    int wid = threadIdx.x >> 6, lane = threadIdx.x & 63;
    int row = blockIdx.x * 4 + wid;
    if (row >= n) return;
    int v = x[row];
    float4 f = *(const float4*)(emb + v * D + lane * 4);
    ushort4 o; o.x = f2b(f.x); o.y = f2b(f.y); o.z = f2b(f.z); o.w = f2b(f.w);
    *(ushort4*)(hb + row * D + lane * 4) = o;
}

// ---------------- W_root (L,K,N) f32 -> Wr (L,N,K) bf16 ----------------
__global__ __launch_bounds__(256)
void convert_wt(const float* __restrict__ W, u16* __restrict__ Wt,
                int total, int K, int N) {
    int idx = blockIdx.x * 256 + threadIdx.x;
    if (idx >= total) return;
    int kk = idx % K;
    int rem = idx / K;
    int nn = rem % N;
    int l  = rem / N;
    Wt[idx] = f2b(W[(l * K + kk) * N + nn]);
}

// ---------------- W_eA (L, A*256, A*256) -> Wcat[((l*A+s)*A+t)][c][k] ----------------
__global__ __launch_bounds__(256)
void convert_cat(const float* __restrict__ W, u16* __restrict__ Wt,
                 int A, int total) {
    int idx = blockIdx.x * 256 + threadIdx.x;
    if (idx >= total) return;
    int k = idx & 255;
    int c = (idx >> 8) & 255;
    int r = idx >> 16;           // (l*A + s)*A + t
    int t = r % A; int ls = r / A; int s = ls % A; int l = ls / A;
    int AD = A * 256;
    Wt[idx] = f2b(W[(size_t)(l * AD + t * 256 + k) * AD + s * 256 + c]);
}

// ---------------- counting sort: CSR (rowptr + edge-id col array) per (type,slot) ------
#define NBINS 100000
#define NSEG 5
#define TOTENT 1200000
#define RPW (NBINS + 1)
#define NSTRIPE 16
#define SBINS (NBINS / NSTRIPE)      // 6250
#define BPT 7

__global__ __launch_bounds__(256)
void zero_counts(int* __restrict__ counts) {
    int i = blockIdx.x * 256 + threadIdx.x;
    if (i < NSEG * NBINS) counts[i] = 0;
}

__device__ __forceinline__ void decode_entry(int i, const int* e2, const int* e3,
                                             int& seg, int& key, int& e, int& is2) {
    if (i < 2 * E2N) {
        int s = i / E2N; e = i - s * E2N;
        seg = s; key = e2[s * E2N + e]; is2 = 1;
    } else {
        int j = i - 2 * E2N; int s = j / E3N; e = j - s * E3N;
        seg = 2 + s; key = e3[s * E3N + e]; is2 = 0;
    }
}

__global__ __launch_bounds__(256)
void hist_kernel(const int* __restrict__ e2, const int* __restrict__ e3,
                 int* __restrict__ counts) {
    int i = blockIdx.x * 256 + threadIdx.x;
    if (i >= TOTENT) return;
    int seg, key, e, is2;
    decode_entry(i, e2, e3, seg, key, e, is2);
    atomicAdd(counts + seg * NBINS + key, 1);
}

__global__ __launch_bounds__(1024)
void scanA(int* __restrict__ counts, int* __restrict__ aux) {
    __shared__ int ps[1024];
    int* base = counts + (blockIdx.x / NSTRIPE) * NBINS + (blockIdx.x % NSTRIPE) * SBINS;
    int t = threadIdx.x;
    int b = t * BPT, en = b + BPT; if (en > SBINS) en = SBINS; if (b > SBINS) b = SBINS;
    int s = 0;
    for (int i = b; i < en; ++i) s += base[i];
    ps[t] = s; __syncthreads();
    for (int off = 1; off < 1024; off <<= 1) {
        int v = ps[t];
        if (t >= off) v += ps[t - off];
        __syncthreads();
        ps[t] = v; __syncthreads();
    }
    int run = (t == 0) ? 0 : ps[t - 1];
    for (int i = b; i < en; ++i) { int c = base[i]; base[i] = run; run += c; }
    if (t == 1023) aux[blockIdx.x] = ps[1023];
}

__global__ __launch_bounds__(256)
void scanB(int* __restrict__ aux) {
    int seg = threadIdx.x;
    if (seg >= NSEG) return;
    int run = 0;
    for (int i = 0; i < NSTRIPE; ++i) {
        int c = aux[seg * NSTRIPE + i];
        aux[seg * NSTRIPE + i] = run; run += c;
    }
}

__global__ __launch_bounds__(1024)
void scanC(int* __restrict__ counts, const int* __restrict__ aux) {
    int off = aux[blockIdx.x];
    if (off == 0) return;
    int* base = counts + (blockIdx.x / NSTRIPE) * NBINS + (blockIdx.x % NSTRIPE) * SBINS;
    int t = threadIdx.x;
    int b = t * BPT, en = b + BPT; if (en > SBINS) en = SBINS; if (b > SBINS) b = SBINS;
    for (int i = b; i < en; ++i) base[i] += off;
}

__global__ __launch_bounds__(256)
void copy_rowptr(const int* __restrict__ counts, int* __restrict__ rp) {
    int i = blockIdx.x * 256 + threadIdx.x;
    if (i >= NSEG * RPW) return;
    int seg = i / RPW, k = i - seg * RPW;
    rp[i] = (k < NBINS) ? counts[seg * NBINS + k] : (seg < 2 ? E2N : E3N);
}

__global__ __launch_bounds__(256)
void scatter_kernel(const int* __restrict__ e2, const int* __restrict__ e3,
                    int* __restrict__ counts, int* __restrict__ sorted2,
                    int* __restrict__ sorted3) {
    int i = blockIdx.x * 256 + threadIdx.x;
    if (i >= TOTENT) return;
    int seg, key, e, is2;
    decode_entry(i, e2, e3, seg, key, e, is2);
    int pos = atomicAdd(counts + seg * NBINS + key, 1);
    if (is2) sorted2[seg * E2N + pos] = e;
    else     sorted3[(seg - 2) * E3N + pos] = e;
}

// ---------------- csrsrc[e] = src_ids[csr[e]] ----------------
__global__ __launch_bounds__(256)
void build_csrsrc(const int* __restrict__ src_ids, const int* __restrict__ csr,
                  int* __restrict__ out, int E) {
    int i = blockIdx.x * 256 + threadIdx.x;
    if (i >= E) return;
    out[i] = src_ids[csr[i]];
}

// ---------------- fused conv: all (s,t) phases of one edge-type ----------------
// Block = 64 dst nodes x 256 out cols, 8 waves, 512 threads.
// Gather (round-12-proven): wave w owns rows w*8..w*8+7 SEQUENTIALLY; per row one
// float4 acc + unroll-4 edge loop of coalesced 512B row reads.
// Diagonal phase (t==s): G_ss[n] = deg_s(n)*h[n] -- no gather.
// MFMA: A from sA (64x264 bf16), wave computes cols wid*32..+31 (acc[4][2], 32 VGPR),
// B from global (L2-resident). Single epilogue RMW for all phases.
#define AP 264            // sA pitch in u16

template<int ARITY>
__global__ __launch_bounds__(512)
void fused_conv(const u16* __restrict__ hb, const int* __restrict__ csrsrc,
                const int* __restrict__ rp, const u16* __restrict__ Wl,
                float* __restrict__ agg, int E) {
    __shared__ __align__(16) u16 sA[64 * AP];    // 33,792 B
    const int m0 = blockIdx.x * 64;
    const int tid = threadIdx.x;
    const int lane = tid & 63;
    const int wid = tid >> 6;          // 0..7
    const int wcol = wid * 32;

    f32x4 acc[4][2];
#pragma unroll
    for (int i = 0; i < 4; ++i)
#pragma unroll
        for (int j = 0; j < 2; ++j)
            acc[i][j] = f32x4{0.f, 0.f, 0.f, 0.f};

#pragma unroll 1
    for (int s = 0; s < ARITY; ++s) {
        const int* rps = rp + s * RPW;
#pragma unroll 1
        for (int t = 0; t < ARITY; ++t) {
            __syncthreads();   // previous phase's MFMA done reading sA
            if (t == s) {
                // diagonal: A row = deg * h[node], coalesced
#pragma unroll 1
                for (int r = 0; r < 8; ++r) {
                    int nl = wid * 8 + r;
                    int node = m0 + nl;
                    ushort4 o = {0, 0, 0, 0};
                    if (node < N_NODES) {
                        float dgf = (float)(rps[node + 1] - rps[node]);
                        ushort4 h = *(const ushort4*)(hb + (size_t)node * 256 + lane * 4);
                        o.x = f2b(dgf * b2f(h.x)); o.y = f2b(dgf * b2f(h.y));
                        o.z = f2b(dgf * b2f(h.z)); o.w = f2b(dgf * b2f(h.w));
                    }
                    *(ushort4*)(sA + nl * AP + lane * 4) = o;
                }
            } else {
                const int* cs = csrsrc + (size_t)(s * ARITY + t) * E;
#pragma unroll 1
                for (int r = 0; r < 8; ++r) {
                    int nl = wid * 8 + r;
                    int node = m0 + nl;
                    float4 a = {0.f, 0.f, 0.f, 0.f};
                    if (node < N_NODES) {
                        int e0 = rps[node], e1 = rps[node + 1];
                        int e = e0;
                        for (; e + 3 < e1; e += 4) {
                            int s0 = cs[e], s1 = cs[e + 1], s2 = cs[e + 2], s3 = cs[e + 3];
                            ushort4 h0 = *(const ushort4*)(hb + (size_t)s0 * 256 + lane * 4);
                            ushort4 h1 = *(const ushort4*)(hb + (size_t)s1 * 256 + lane * 4);
                            ushort4 h2 = *(const ushort4*)(hb + (size_t)s2 * 256 + lane * 4);
                            ushort4 h3 = *(const ushort4*)(hb + (size_t)s3 * 256 + lane * 4);
                            a.x += (b2f(h0.x) + b2f(h1.x)) + (b2f(h2.x) + b2f(h3.x));
                            a.y += (b2f(h0.y) + b2f(h1.y)) + (b2f(h2.y) + b2f(h3.y));
                            a.z += (b2f(h0.z) + b2f(h1.z)) + (b2f(h2.z) + b2f(h3.z));
                            a.w += (b2f(h0.w) + b2f(h1.w)) + (b2f(h2.w) + b2f(h3.w));
                        }
                        for (; e < e1; ++e) {
                            int s0 = cs[e];
                            ushort4 h0 = *(const ushort4*)(hb + (size_t)s0 * 256 + lane * 4);
                            a.x += b2f(h0.x); a.y += b2f(h0.y);
                            a.z += b2f(h0.z); a.w += b2f(h0.w);
                        }
                    }
                    ushort4 o;
                    o.x = f2b(a.x); o.y = f2b(a.y); o.z = f2b(a.z); o.w = f2b(a.w);
                    *(ushort4*)(sA + nl * AP + lane * 4) = o;
                }
            }
            __syncthreads();   // sA ready
            // ---- MFMA: A from LDS, B cols wcol..wcol+31 from global (L2) ----
            const u16* Bt = Wl + (size_t)(s * ARITY + t) * 65536;
#pragma unroll
            for (int k0 = 0; k0 < 256; k0 += 64) {
#pragma unroll
                for (int ks = 0; ks < 2; ++ks) {
                    const int koff = k0 + ks * 32 + (lane >> 4) * 8;
                    bf16x8 af[4], bf[2];
#pragma unroll
                    for (int mi = 0; mi < 4; ++mi)
                        af[mi] = *(const bf16x8*)(sA + (mi * 16 + (lane & 15)) * AP + koff);
#pragma unroll
                    for (int ni = 0; ni < 2; ++ni)
                        bf[ni] = *(const bf16x8*)(Bt + (size_t)(wcol + ni * 16 + (lane & 15)) * 256 + koff);
#pragma unroll
                    for (int mi = 0; mi < 4; ++mi)
#pragma unroll
                        for (int ni = 0; ni < 2; ++ni)
                            acc[mi][ni] = __builtin_amdgcn_mfma_f32_16x16x32_bf16(
                                af[mi], bf[ni], acc[mi][ni], 0, 0, 0);
                }
            }
        }
    }

    // epilogue: one RMW for all (s,t) phases (block-exclusive rows)
    const int colb = wcol + (lane & 15);
#pragma unroll
    for (int mi = 0; mi < 4; ++mi) {
        int mbase = m0 + mi * 16 + ((lane >> 4) << 2);
#pragma unroll
        for (int r = 0; r < 4; ++r) {
            int m = mbase + r;
            if (m < N_NODES) {
#pragma unroll
                for (int ni = 0; ni < 2; ++ni)
                    agg[(size_t)m * 256 + colb + ni * 16] += acc[mi][ni][r];
            }
        }
    }
}

// ---------------- root GEMM (m97-style, INIT): agg = hb @ Wr^T ----------------
__global__ __launch_bounds__(256)
void gemm128(const u16* __restrict__ A, const u16* __restrict__ B,
             float* __restrict__ aggr, int M) {
    __shared__ __align__(16) u16 sA[128 * 64];
    __shared__ __align__(16) u16 sB[128 * 64];
    const int bid = blockIdx.x;
    const int mt = bid >> 1;
    const int nt = bid & 1;
    const int m0 = mt * 128;
    const int n0 = nt * 128;
    const int tid = threadIdx.x;
    const int lane = tid & 63;
    const int wid = tid >> 6;
    const int wm = (wid >> 1) * 64;
    const int wn = (wid & 1) * 64;
    const int lrow8 = lane >> 3;
    const int lcol  = (lane & 7) * 8;

    f32x4 acc[4][4];
#pragma unroll
    for (int i = 0; i < 4; ++i)
#pragma unroll
        for (int j = 0; j < 4; ++j)
            acc[i][j] = f32x4{0.f, 0.f, 0.f, 0.f};

    for (int k0 = 0; k0 < 256; k0 += 64) {
        __syncthreads();
#pragma unroll
        for (int i = 0; i < 4; ++i) {
            int row = wid * 32 + i * 8;
            int ar = m0 + row + lrow8; ar = (ar < M) ? ar : (M - 1);
            gload16(A + (size_t)ar * 256 + k0 + lcol, sA + row * 64);
            gload16(B + (size_t)(n0 + row + lrow8) * 256 + k0 + lcol, sB + row * 64);
        }
        __syncthreads();
#pragma unroll
        for (int ks = 0; ks < 2; ++ks) {
            const int koff = ks * 32 + (lane >> 4) * 8;
            bf16x8 af[4], bf[4];
#pragma unroll
            for (int mi = 0; mi < 4; ++mi)
                af[mi] = *(const bf16x8*)(sA + (wm + mi * 16 + (lane & 15)) * 64 + koff);
#pragma unroll
            for (int ni = 0; ni < 4; ++ni)
                bf[ni] = *(const bf16x8*)(sB + (wn + ni * 16 + (lane & 15)) * 64 + koff);
#pragma unroll
            for (int mi = 0; mi < 4; ++mi)
#pragma unroll
                for (int ni = 0; ni < 4; ++ni)
                    acc[mi][ni] = __builtin_amdgcn_mfma_f32_16x16x32_bf16(
                        af[mi], bf[ni], acc[mi][ni], 0, 0, 0);
        }
    }

    const int colb = n0 + wn + (lane & 15);
#pragma unroll
    for (int mi = 0; mi < 4; ++mi) {
        int mbase = m0 + wm + mi * 16 + ((lane >> 4) << 2);
#pragma unroll
        for (int r = 0; r < 4; ++r) {
            int m = mbase + r;
            if (m < M) {
#pragma unroll
                for (int ni = 0; ni < 4; ++ni)
                    aggr[(size_t)m * 256 + colb + ni * 16] = acc[mi][ni][r];
            }
        }
    }
}

// ---------------- h = LN(relu(agg)) -> bf16 ----------------
__global__ __launch_bounds__(256)
void relu_ln_kernel(const float* __restrict__ agg, const float* __restrict__ g,
                    const float* __restrict__ b, u16* __restrict__ hb, int n) {
    int wid = threadIdx.x >> 6, lane = threadIdx.x & 63;
    int row = blockIdx.x * 4 + wid;
    if (row >= n) return;
    float4 v = *(const float4*)(agg + row * D + lane * 4);
    v.x = fmaxf(v.x, 0.f); v.y = fmaxf(v.y, 0.f);
    v.z = fmaxf(v.z, 0.f); v.w = fmaxf(v.w, 0.f);
    float s  = v.x + v.y + v.z + v.w;
    float s2 = v.x * v.x + v.y * v.y + v.z * v.z + v.w * v.w;
#pragma unroll
    for (int off = 1; off < 64; off <<= 1) {
        s  += __shfl_xor(s, off);
        s2 += __shfl_xor(s2, off);
    }
    float mu = s * 0.00390625f;
    float var = s2 * 0.00390625f - mu * mu;
    float rs = rsqrtf(var + 1e-5f);
    float4 gg = *(const float4*)(g + lane * 4);
    float4 bb = *(const float4*)(b + lane * 4);
    ushort4 o;
    o.x = f2b((v.x - mu) * rs * gg.x + bb.x);
    o.y = f2b((v.y - mu) * rs * gg.y + bb.y);
    o.z = f2b((v.z - mu) * rs * gg.z + bb.z);
    o.w = f2b((v.w - mu) * rs * gg.w + bb.w);
    *(ushort4*)(hb + row * D + lane * 4) = o;
}

// ---------------- head layers ----------------
__global__ __launch_bounds__(256)
void head_layer(const u16* __restrict__ hb, const int* __restrict__ tgt,
                const float* __restrict__ inf,
                const float* __restrict__ W, const float* __restrict__ bias,
                const float* __restrict__ g, const float* __restrict__ beta,
                float* __restrict__ out, int gather) {
    __shared__ float xr[256];
    __shared__ float sm1[4], sm2[4];
    int t = blockIdx.x, tid = threadIdx.x;
    if (gather) { int node = tgt[t]; xr[tid] = b2f(hb[node * D + tid]); }
    else        { xr[tid] = inf[t * D + tid]; }
    __syncthreads();
    float a = bias[tid];
#pragma unroll 8
    for (int k = 0; k < 256; ++k) a = fmaf(xr[k], W[k * 256 + tid], a);
    float s = a, s2 = a * a;
#pragma unroll
    for (int off = 1; off < 64; off <<= 1) {
        s  += __shfl_xor(s, off);
        s2 += __shfl_xor(s2, off);
    }
    int wid = tid >> 6, lane = tid & 63;
    if (lane == 0) { sm1[wid] = s; sm2[wid] = s2; }
    __syncthreads();
    s  = sm1[0] + sm1[1] + sm1[2] + sm1[3];
    s2 = sm2[0] + sm2[1] + sm2[2] + sm2[3];
    float mu = s * 0.00390625f;
    float var = s2 * 0.00390625f - mu * mu;
    float rs = rsqrtf(var + 1e-5f);
    float y = (a - mu) * rs * g[tid] + beta[tid];
    out[t * 256 + tid] = fmaxf(y, 0.f);
}

__global__ __launch_bounds__(256)
void head_out(const float* __restrict__ in, const float* __restrict__ ow,
              const float* __restrict__ ob, float* __restrict__ out, int T) {
    int wid = threadIdx.x >> 6, lane = threadIdx.x & 63;
    int t = blockIdx.x * 4 + wid;
    if (t >= T) return;
    float4 v = *(const float4*)(in + t * D + lane * 4);
    float4 w = *(const float4*)(ow + lane * 4);
    float s = v.x * w.x + v.y * w.y + v.z * w.z + v.w * w.w;
#pragma unroll
    for (int off = 1; off < 64; off <<= 1) s += __shfl_xor(s, off);
    if (lane == 0) out[t] = s + ob[0];
}

extern "C" void kernel_launch(void* const* d_in, const int* in_sizes, int n_in,
                              void* d_out, int out_size, void* d_ws, size_t ws_size,
                              hipStream_t stream) {
    (void)in_sizes; (void)n_in; (void)out_size; (void)ws_size;
    const int*   x      = (const int*)d_in[0];
    const int*   e2     = (const int*)d_in[2];
    const int*   e3     = (const int*)d_in[3];
    const int*   tgt    = (const int*)d_in[4];
    const float* emb    = (const float*)d_in[5];
    const float* W_root = (const float*)d_in[6];
    const float* W_e2   = (const float*)d_in[7];
    const float* W_e3   = (const float*)d_in[8];
    const float* ln_g   = (const float*)d_in[9];
    const float* ln_b   = (const float*)d_in[10];
    const float* reg_W  = (const float*)d_in[11];
    const float* reg_b  = (const float*)d_in[12];
    const float* rln_g  = (const float*)d_in[13];
    const float* rln_b  = (const float*)d_in[14];
    const float* out_W  = (const float*)d_in[15];
    const float* out_b  = (const float*)d_in[16];
    float* out = (float*)d_out;

    // workspace layout — top 183,837,184 B (round-11/12/13-proven)
    char* ws = (char*)d_ws;
    float* agg     = (float*)(ws);                    // 102,400,000 B
    int*   counts  = (int*)  (ws);                    // aliases agg (dead until layer 0)
    u16*   hb      = (u16*)  (ws + 102400000);        //  51,200,000
    u16*   Wr      = (u16*)  (ws + 153600000);        //     524,288
    u16*   W2c     = (u16*)  (ws + 154124288);        //   2,097,152
    u16*   W3c     = (u16*)  (ws + 156221440);        //   4,718,592
    int*   sorted2 = (int*)  (ws + 160940032);        //   2,400,000
    int*   sorted3 = (int*)  (ws + 163340032);        //   2,400,000
    int*   rp      = (int*)  (ws + 165740032);        //   2,000,020 -> pad 2,000,128
    int*   aux     = (int*)  (ws + 167740160);        //         320 -> pad 1,024
    int*   csrsrc2 = (int*)  (ws + 167741184);        //   4,800,000 (2s x 2t x E2N)
    int*   csrsrc3 = (int*)  (ws + 172541184);        //   7,200,000 (3s x 3t x E3N)
    float* t0      = (float*)(ws + 179741184);        //   2,048,000
    float* t1      = (float*)(ws + 181789184);        //   2,048,000

    embed_kernel<<<N_NODES / 4, 256, 0, stream>>>(x, emb, hb, N_NODES);
    convert_wt<<<(NLAYER * 256 * 256 + 255) / 256, 256, 0, stream>>>(W_root, Wr, NLAYER * 256 * 256, 256, 256);
    convert_cat<<<(NLAYER * 4 * 65536 + 255) / 256, 256, 0, stream>>>(W_e2, W2c, 2, NLAYER * 4 * 65536);
    convert_cat<<<(NLAYER * 9 * 65536 + 255) / 256, 256, 0, stream>>>(W_e3, W3c, 3, NLAYER * 9 * 65536);

    zero_counts<<<(NSEG * NBINS + 255) / 256, 256, 0, stream>>>(counts);
    hist_kernel<<<(TOTENT + 255) / 256, 256, 0, stream>>>(e2, e3, counts);
    scanA<<<NSEG * NSTRIPE, 1024, 0, stream>>>(counts, aux);
    scanB<<<1, 256, 0, stream>>>(aux);
    scanC<<<NSEG * NSTRIPE, 1024, 0, stream>>>(counts, aux);
    copy_rowptr<<<(NSEG * RPW + 255) / 256, 256, 0, stream>>>(counts, rp);
    scatter_kernel<<<(TOTENT + 255) / 256, 256, 0, stream>>>(e2, e3, counts, sorted2, sorted3);

    for (int s = 0; s < 2; ++s)
        for (int t = 0; t < 2; ++t)
            build_csrsrc<<<(E2N + 255) / 256, 256, 0, stream>>>(
                e2 + (size_t)t * E2N, sorted2 + (size_t)s * E2N,
                csrsrc2 + (size_t)(s * 2 + t) * E2N, E2N);
    for (int s = 0; s < 3; ++s)
        for (int t = 0; t < 3; ++t)
            build_csrsrc<<<(E3N + 255) / 256, 256, 0, stream>>>(
                e3 + (size_t)t * E3N, sorted3 + (size_t)s * E3N,
                csrsrc3 + (size_t)(s * 3 + t) * E3N, E3N);

    const int mgrid = ((N_NODES + 127) / 128) * 2;   // 1564 (root)
    const int fgrid = (N_NODES + 63) / 64;           // 1563 (fused conv)

    for (int l = 0; l < NLAYER; ++l) {
        gemm128<<<mgrid, 256, 0, stream>>>(hb, Wr + (size_t)l * 65536, agg, N_NODES);
        fused_conv<2><<<fgrid, 512, 0, stream>>>(
            hb, csrsrc2, rp, W2c + (size_t)l * 4 * 65536, agg, E2N);
        fused_conv<3><<<fgrid, 512, 0, stream>>>(
            hb, csrsrc3, rp + 2 * RPW, W3c + (size_t)l * 9 * 65536, agg, E3N);
        relu_ln_kernel<<<N_NODES / 4, 256, 0, stream>>>(agg, ln_g + l * D, ln_b + l * D, hb, N_NODES);
    }

    head_layer<<<TGT, 256, 0, stream>>>(hb, tgt, nullptr, reg_W, reg_b, rln_g, rln_b, t0, 1);
    head_layer<<<TGT, 256, 0, stream>>>(nullptr, nullptr, t0, reg_W + 65536, reg_b + 256, rln_g + 256, rln_b + 256, t1, 0);
    head_out<<<(TGT + 3) / 4, 256, 0, stream>>>(t1, out_W, out_b, out, TGT);
}

// Round 16
// 3364.590 us; speedup vs baseline: 3.6313x; 1.0860x over previous
//
#include <hip/hip_runtime.h>

typedef unsigned short u16;
typedef __bf16 bf16x8 __attribute__((ext_vector_type(8)));
typedef float f32x4 __attribute__((ext_vector_type(4)));

#define N_NODES 100000
#define D 256
#define NLAYER 4
#define E2N 300000
#define E3N 200000
#define TGT 2000

__device__ __forceinline__ u16 f2b(float f) {
    union { float f; unsigned u; } v; v.f = f;
    unsigned r = v.u + 0x7FFFu + ((v.u >> 16) & 1u);
    return (u16)(r >> 16);
}
__device__ __forceinline__ float b2f(u16 u) {
    union { unsigned u; float f; } v; v.u = ((unsigned)u) << 16; return v.f;
}

// async global->LDS, 16B per lane (lds dest = uniform base + lane*16)
__device__ __forceinline__ void gload16(const void* g, void* l) {
    __builtin_amdgcn_global_load_lds(
        (const __attribute__((address_space(1))) void*)g,
        (__attribute__((address_space(3))) void*)l, 16, 0, 0);
}

// ---------------- embedding gather ----------------
__global__ __launch_bounds__(256)
void embed_kernel(const int* __restrict__ x, const float* __restrict__ emb,
                  u16* __restrict__ hb, int n) {
    int wid = threadIdx.x >> 6, lane = threadIdx.x & 63;
    int row = blockIdx.x * 4 + wid;
    if (row >= n) return;
    int v = x[row];
    float4 f = *(const float4*)(emb + v * D + lane * 4);
    ushort4 o; o.x = f2b(f.x); o.y = f2b(f.y); o.z = f2b(f.z); o.w = f2b(f.w);
    *(ushort4*)(hb + row * D + lane * 4) = o;
}

// ---------------- W_root (L,K,N) f32 -> Wr (L,N,K) bf16 ----------------
__global__ __launch_bounds__(256)
void convert_wt(const float* __restrict__ W, u16* __restrict__ Wt,
                int total, int K, int N) {
    int idx = blockIdx.x * 256 + threadIdx.x;
    if (idx >= total) return;
    int kk = idx % K;
    int rem = idx / K;
    int nn = rem % N;
    int l  = rem / N;
    Wt[idx] = f2b(W[(l * K + kk) * N + nn]);
}

// ---------------- W_eA (L, A*256, A*256) -> Wcat[((l*A+s)*A+t)][c][k] ----------------
__global__ __launch_bounds__(256)
void convert_cat(const float* __restrict__ W, u16* __restrict__ Wt,
                 int A, int total) {
    int idx = blockIdx.x * 256 + threadIdx.x;
    if (idx >= total) return;
    int k = idx & 255;
    int c = (idx >> 8) & 255;
    int r = idx >> 16;           // (l*A + s)*A + t
    int t = r % A; int ls = r / A; int s = ls % A; int l = ls / A;
    int AD = A * 256;
    Wt[idx] = f2b(W[(size_t)(l * AD + t * 256 + k) * AD + s * 256 + c]);
}

// ---------------- counting sort: CSR (rowptr + edge-id col array) per (type,slot) ------
#define NBINS 100000
#define NSEG 5
#define TOTENT 1200000
#define RPW (NBINS + 1)
#define NSTRIPE 16
#define SBINS (NBINS / NSTRIPE)      // 6250
#define BPT 7

__global__ __launch_bounds__(256)
void zero_counts(int* __restrict__ counts) {
    int i = blockIdx.x * 256 + threadIdx.x;
    if (i < NSEG * NBINS) counts[i] = 0;
}

__device__ __forceinline__ void decode_entry(int i, const int* e2, const int* e3,
                                             int& seg, int& key, int& e, int& is2) {
    if (i < 2 * E2N) {
        int s = i / E2N; e = i - s * E2N;
        seg = s; key = e2[s * E2N + e]; is2 = 1;
    } else {
        int j = i - 2 * E2N; int s = j / E3N; e = j - s * E3N;
        seg = 2 + s; key = e3[s * E3N + e]; is2 = 0;
    }
}

__global__ __launch_bounds__(256)
void hist_kernel(const int* __restrict__ e2, const int* __restrict__ e3,
                 int* __restrict__ counts) {
    int i = blockIdx.x * 256 + threadIdx.x;
    if (i >= TOTENT) return;
    int seg, key, e, is2;
    decode_entry(i, e2, e3, seg, key, e, is2);
    atomicAdd(counts + seg * NBINS + key, 1);
}

__global__ __launch_bounds__(1024)
void scanA(int* __restrict__ counts, int* __restrict__ aux) {
    __shared__ int ps[1024];
    int* base = counts + (blockIdx.x / NSTRIPE) * NBINS + (blockIdx.x % NSTRIPE) * SBINS;
    int t = threadIdx.x;
    int b = t * BPT, en = b + BPT; if (en > SBINS) en = SBINS; if (b > SBINS) b = SBINS;
    int s = 0;
    for (int i = b; i < en; ++i) s += base[i];
    ps[t] = s; __syncthreads();
    for (int off = 1; off < 1024; off <<= 1) {
        int v = ps[t];
        if (t >= off) v += ps[t - off];
        __syncthreads();
        ps[t] = v; __syncthreads();
    }
    int run = (t == 0) ? 0 : ps[t - 1];
    for (int i = b; i < en; ++i) { int c = base[i]; base[i] = run; run += c; }
    if (t == 1023) aux[blockIdx.x] = ps[1023];
}

__global__ __launch_bounds__(256)
void scanB(int* __restrict__ aux) {
    int seg = threadIdx.x;
    if (seg >= NSEG) return;
    int run = 0;
    for (int i = 0; i < NSTRIPE; ++i) {
        int c = aux[seg * NSTRIPE + i];
        aux[seg * NSTRIPE + i] = run; run += c;
    }
}

__global__ __launch_bounds__(1024)
void scanC(int* __restrict__ counts, const int* __restrict__ aux) {
    int off = aux[blockIdx.x];
    if (off == 0) return;
    int* base = counts + (blockIdx.x / NSTRIPE) * NBINS + (blockIdx.x % NSTRIPE) * SBINS;
    int t = threadIdx.x;
    int b = t * BPT, en = b + BPT; if (en > SBINS) en = SBINS; if (b > SBINS) b = SBINS;
    for (int i = b; i < en; ++i) base[i] += off;
}

__global__ __launch_bounds__(256)
void copy_rowptr(const int* __restrict__ counts, int* __restrict__ rp) {
    int i = blockIdx.x * 256 + threadIdx.x;
    if (i >= NSEG * RPW) return;
    int seg = i / RPW, k = i - seg * RPW;
    rp[i] = (k < NBINS) ? counts[seg * NBINS + k] : (seg < 2 ? E2N : E3N);
}

__global__ __launch_bounds__(256)
void scatter_kernel(const int* __restrict__ e2, const int* __restrict__ e3,
                    int* __restrict__ counts, int* __restrict__ sorted2,
                    int* __restrict__ sorted3) {
    int i = blockIdx.x * 256 + threadIdx.x;
    if (i >= TOTENT) return;
    int seg, key, e, is2;
    decode_entry(i, e2, e3, seg, key, e, is2);
    int pos = atomicAdd(counts + seg * NBINS + key, 1);
    if (is2) sorted2[seg * E2N + pos] = e;
    else     sorted3[(seg - 2) * E3N + pos] = e;
}

// ---------------- csrsrc[e] = src_ids[csr[e]] ----------------
__global__ __launch_bounds__(256)
void build_csrsrc(const int* __restrict__ src_ids, const int* __restrict__ csr,
                  int* __restrict__ out, int E) {
    int i = blockIdx.x * 256 + threadIdx.x;
    if (i >= E) return;
    out[i] = src_ids[csr[i]];
}

// ---------------- fused conv: all (s,t) phases of one edge-type ----------------
// Block = 64 dst nodes x 256 out cols, 8 waves, 512 threads.
// Gather (round 16): wave's 8 rows own a CONTIGUOUS csr range. Lanes preload up to
// 128 edge indices (2 coalesced loads) + 9 rowptrs; __shfl replaces index loads in
// the address chain. Flat edge walk in batches of 8 -> 8 independent row loads in
// flight; segmented accumulation with flush-on-row-boundary (boundary via shfl,
// no dynamic register-array indexing). Wave-uniform control flow.
// Diagonal phase (t==s): G_ss[n] = deg_s(n)*h[n] -- no gather.
// MFMA: A from sA (64x264 bf16), wave computes cols wid*32..+31 (acc[4][2]),
// B from global (L2-resident). Single epilogue RMW for all phases.
#define AP 264            // sA pitch in u16

template<int ARITY>
__global__ __launch_bounds__(512)
void fused_conv(const u16* __restrict__ hb, const int* __restrict__ csrsrc,
                const int* __restrict__ rp, const u16* __restrict__ Wl,
                float* __restrict__ agg, int E) {
    __shared__ __align__(16) u16 sA[64 * AP];    // 33,792 B
    const int m0 = blockIdx.x * 64;
    const int tid = threadIdx.x;
    const int lane = tid & 63;
    const int wid = tid >> 6;          // 0..7
    const int wcol = wid * 32;
    const int node0 = m0 + wid * 8;    // this wave's 8 dst rows

    f32x4 acc[4][2];
#pragma unroll
    for (int i = 0; i < 4; ++i)
#pragma unroll
        for (int j = 0; j < 2; ++j)
            acc[i][j] = f32x4{0.f, 0.f, 0.f, 0.f};

#pragma unroll 1
    for (int s = 0; s < ARITY; ++s) {
        const int* rps = rp + s * RPW;
        // lane-parallel rowptr fetch: lanes 0..8 load rps[node0..node0+8] (clamped)
        int nidx = node0 + lane;
        nidx = (nidx > N_NODES) ? N_NODES : nidx;
        int rv = (lane <= 8) ? rps[nidx] : 0;
        const int ebase = __shfl(rv, 0);
        const int eend  = __shfl(rv, 8);
        const int nE    = eend - ebase;

#pragma unroll 1
        for (int t = 0; t < ARITY; ++t) {
            __syncthreads();   // previous phase's MFMA done reading sA
            if (t == s) {
                // diagonal: A row = deg * h[node], coalesced (deg from shuffled rowptrs)
#pragma unroll 1
                for (int r = 0; r < 8; ++r) {
                    int nl = wid * 8 + r;
                    int node = m0 + nl;
                    ushort4 o = {0, 0, 0, 0};
                    if (node < N_NODES) {
                        float dgf = (float)(__shfl(rv, r + 1) - __shfl(rv, r));
                        ushort4 h = *(const ushort4*)(hb + (size_t)node * 256 + lane * 4);
                        o.x = f2b(dgf * b2f(h.x)); o.y = f2b(dgf * b2f(h.y));
                        o.z = f2b(dgf * b2f(h.z)); o.w = f2b(dgf * b2f(h.w));
                    }
                    *(ushort4*)(sA + nl * AP + lane * 4) = o;
                }
            } else {
                const int* cs = csrsrc + (size_t)(s * ARITY + t) * E;
                // preload up to 128 edge indices with 2 coalesced lane loads
                int myi0 = (lane < nE) ? cs[ebase + lane] : 0;
                int myi1 = (lane + 64 < nE) ? cs[ebase + 64 + lane] : 0;

                int currow = 0;
                int rowend = __shfl(rv, 1) - ebase;    // end of row 0 (relative)
                float4 run = {0.f, 0.f, 0.f, 0.f};
#pragma unroll 1
                for (int eb = 0; eb < nE; eb += 8) {
                    // issue 8 independent row loads (addresses from shuffles)
                    ushort4 hv[8];
#pragma unroll
                    for (int j = 0; j < 8; ++j) {
                        int e = eb + j;
                        int src;
                        if (e >= nE)      src = 0;                       // dummy, discarded
                        else if (e < 64)  src = __shfl(myi0, e);
                        else if (e < 128) src = __shfl(myi1, e - 64);
                        else              src = cs[ebase + e];           // rare overflow
                        hv[j] = *(const ushort4*)(hb + (size_t)src * 256 + lane * 4);
                    }
                    // segmented accumulation with flush on row boundary
#pragma unroll
                    for (int j = 0; j < 8; ++j) {
                        int e = eb + j;
                        if (e < nE) {
                            while (e >= rowend) {
                                ushort4 o;
                                o.x = f2b(run.x); o.y = f2b(run.y);
                                o.z = f2b(run.z); o.w = f2b(run.w);
                                *(ushort4*)(sA + (wid * 8 + currow) * AP + lane * 4) = o;
                                run = float4{0.f, 0.f, 0.f, 0.f};
                                ++currow;
                                rowend = __shfl(rv, currow + 1) - ebase;
                            }
                            run.x += b2f(hv[j].x); run.y += b2f(hv[j].y);
                            run.z += b2f(hv[j].z); run.w += b2f(hv[j].w);
                        }
                    }
                }
                // flush remaining rows (current partial + trailing empties)
                while (currow < 8) {
                    ushort4 o;
                    o.x = f2b(run.x); o.y = f2b(run.y);
                    o.z = f2b(run.z); o.w = f2b(run.w);
                    *(ushort4*)(sA + (wid * 8 + currow) * AP + lane * 4) = o;
                    run = float4{0.f, 0.f, 0.f, 0.f};
                    ++currow;
                }
            }
            __syncthreads();   // sA ready
            // ---- MFMA: A from LDS, B cols wcol..wcol+31 from global (L2) ----
            const u16* Bt = Wl + (size_t)(s * ARITY + t) * 65536;
#pragma unroll
            for (int k0 = 0; k0 < 256; k0 += 64) {
#pragma unroll
                for (int ks = 0; ks < 2; ++ks) {
                    const int koff = k0 + ks * 32 + (lane >> 4) * 8;
                    bf16x8 af[4], bf[2];
#pragma unroll
                    for (int mi = 0; mi < 4; ++mi)
                        af[mi] = *(const bf16x8*)(sA + (mi * 16 + (lane & 15)) * AP + koff);
#pragma unroll
                    for (int ni = 0; ni < 2; ++ni)
                        bf[ni] = *(const bf16x8*)(Bt + (size_t)(wcol + ni * 16 + (lane & 15)) * 256 + koff);
#pragma unroll
                    for (int mi = 0; mi < 4; ++mi)
#pragma unroll
                        for (int ni = 0; ni < 2; ++ni)
                            acc[mi][ni] = __builtin_amdgcn_mfma_f32_16x16x32_bf16(
                                af[mi], bf[ni], acc[mi][ni], 0, 0, 0);
                }
            }
        }
    }

    // epilogue: one RMW for all (s,t) phases (block-exclusive rows)
    const int colb = wcol + (lane & 15);
#pragma unroll
    for (int mi = 0; mi < 4; ++mi) {
        int mbase = m0 + mi * 16 + ((lane >> 4) << 2);
#pragma unroll
        for (int r = 0; r < 4; ++r) {
            int m = mbase + r;
            if (m < N_NODES) {
#pragma unroll
                for (int ni = 0; ni < 2; ++ni)
                    agg[(size_t)m * 256 + colb + ni * 16] += acc[mi][ni][r];
            }
        }
    }
}

// ---------------- root GEMM (m97-style, INIT): agg = hb @ Wr^T ----------------
__global__ __launch_bounds__(256)
void gemm128(const u16* __restrict__ A, const u16* __restrict__ B,
             float* __restrict__ aggr, int M) {
    __shared__ __align__(16) u16 sA[128 * 64];
    __shared__ __align__(16) u16 sB[128 * 64];
    const int bid = blockIdx.x;
    const int mt = bid >> 1;
    const int nt = bid & 1;
    const int m0 = mt * 128;
    const int n0 = nt * 128;
    const int tid = threadIdx.x;
    const int lane = tid & 63;
    const int wid = tid >> 6;
    const int wm = (wid >> 1) * 64;
    const int wn = (wid & 1) * 64;
    const int lrow8 = lane >> 3;
    const int lcol  = (lane & 7) * 8;

    f32x4 acc[4][4];
#pragma unroll
    for (int i = 0; i < 4; ++i)
#pragma unroll
        for (int j = 0; j < 4; ++j)
            acc[i][j] = f32x4{0.f, 0.f, 0.f, 0.f};

    for (int k0 = 0; k0 < 256; k0 += 64) {
        __syncthreads();
#pragma unroll
        for (int i = 0; i < 4; ++i) {
            int row = wid * 32 + i * 8;
            int ar = m0 + row + lrow8; ar = (ar < M) ? ar : (M - 1);
            gload16(A + (size_t)ar * 256 + k0 + lcol, sA + row * 64);
            gload16(B + (size_t)(n0 + row + lrow8) * 256 + k0 + lcol, sB + row * 64);
        }
        __syncthreads();
#pragma unroll
        for (int ks = 0; ks < 2; ++ks) {
            const int koff = ks * 32 + (lane >> 4) * 8;
            bf16x8 af[4], bf[4];
#pragma unroll
            for (int mi = 0; mi < 4; ++mi)
                af[mi] = *(const bf16x8*)(sA + (wm + mi * 16 + (lane & 15)) * 64 + koff);
#pragma unroll
            for (int ni = 0; ni < 4; ++ni)
                bf[ni] = *(const bf16x8*)(sB + (wn + ni * 16 + (lane & 15)) * 64 + koff);
#pragma unroll
            for (int mi = 0; mi < 4; ++mi)
#pragma unroll
                for (int ni = 0; ni < 4; ++ni)
                    acc[mi][ni] = __builtin_amdgcn_mfma_f32_16x16x32_bf16(
                        af[mi], bf[ni], acc[mi][ni], 0, 0, 0);
        }
    }

    const int colb = n0 + wn + (lane & 15);
#pragma unroll
    for (int mi = 0; mi < 4; ++mi) {
        int mbase = m0 + wm + mi * 16 + ((lane >> 4) << 2);
#pragma unroll
        for (int r = 0; r < 4; ++r) {
            int m = mbase + r;
            if (m < M) {
#pragma unroll
                for (int ni = 0; ni < 4; ++ni)
                    aggr[(size_t)m * 256 + colb + ni * 16] = acc[mi][ni][r];
            }
        }
    }
}

// ---------------- h = LN(relu(agg)) -> bf16 ----------------
__global__ __launch_bounds__(256)
void relu_ln_kernel(const float* __restrict__ agg, const float* __restrict__ g,
                    const float* __restrict__ b, u16* __restrict__ hb, int n) {
    int wid = threadIdx.x >> 6, lane = threadIdx.x & 63;
    int row = blockIdx.x * 4 + wid;
    if (row >= n) return;
    float4 v = *(const float4*)(agg + row * D + lane * 4);
    v.x = fmaxf(v.x, 0.f); v.y = fmaxf(v.y, 0.f);
    v.z = fmaxf(v.z, 0.f); v.w = fmaxf(v.w, 0.f);
    float s  = v.x + v.y + v.z + v.w;
    float s2 = v.x * v.x + v.y * v.y + v.z * v.z + v.w * v.w;
#pragma unroll
    for (int off = 1; off < 64; off <<= 1) {
        s  += __shfl_xor(s, off);
        s2 += __shfl_xor(s2, off);
    }
    float mu = s * 0.00390625f;
    float var = s2 * 0.00390625f - mu * mu;
    float rs = rsqrtf(var + 1e-5f);
    float4 gg = *(const float4*)(g + lane * 4);
    float4 bb = *(const float4*)(b + lane * 4);
    ushort4 o;
    o.x = f2b((v.x - mu) * rs * gg.x + bb.x);
    o.y = f2b((v.y - mu) * rs * gg.y + bb.y);
    o.z = f2b((v.z - mu) * rs * gg.z + bb.z);
    o.w = f2b((v.w - mu) * rs * gg.w + bb.w);
    *(ushort4*)(hb + row * D + lane * 4) = o;
}

// ---------------- head layers ----------------
__global__ __launch_bounds__(256)
void head_layer(const u16* __restrict__ hb, const int* __restrict__ tgt,
                const float* __restrict__ inf,
                const float* __restrict__ W, const float* __restrict__ bias,
                const float* __restrict__ g, const float* __restrict__ beta,
                float* __restrict__ out, int gather) {
    __shared__ float xr[256];
    __shared__ float sm1[4], sm2[4];
    int t = blockIdx.x, tid = threadIdx.x;
    if (gather) { int node = tgt[t]; xr[tid] = b2f(hb[node * D + tid]); }
    else        { xr[tid] = inf[t * D + tid]; }
    __syncthreads();
    float a = bias[tid];
#pragma unroll 8
    for (int k = 0; k < 256; ++k) a = fmaf(xr[k], W[k * 256 + tid], a);
    float s = a, s2 = a * a;
#pragma unroll
    for (int off = 1; off < 64; off <<= 1) {
        s  += __shfl_xor(s, off);
        s2 += __shfl_xor(s2, off);
    }
    int wid = tid >> 6, lane = tid & 63;
    if (lane == 0) { sm1[wid] = s; sm2[wid] = s2; }
    __syncthreads();
    s  = sm1[0] + sm1[1] + sm1[2] + sm1[3];
    s2 = sm2[0] + sm2[1] + sm2[2] + sm2[3];
    float mu = s * 0.00390625f;
    float var = s2 * 0.00390625f - mu * mu;
    float rs = rsqrtf(var + 1e-5f);
    float y = (a - mu) * rs * g[tid] + beta[tid];
    out[t * 256 + tid] = fmaxf(y, 0.f);
}

__global__ __launch_bounds__(256)
void head_out(const float* __restrict__ in, const float* __restrict__ ow,
              const float* __restrict__ ob, float* __restrict__ out, int T) {
    int wid = threadIdx.x >> 6, lane = threadIdx.x & 63;
    int t = blockIdx.x * 4 + wid;
    if (t >= T) return;
    float4 v = *(const float4*)(in + t * D + lane * 4);
    float4 w = *(const float4*)(ow + lane * 4);
    float s = v.x * w.x + v.y * w.y + v.z * w.z + v.w * w.w;
#pragma unroll
    for (int off = 1; off < 64; off <<= 1) s += __shfl_xor(s, off);
    if (lane == 0) out[t] = s + ob[0];
}

extern "C" void kernel_launch(void* const* d_in, const int* in_sizes, int n_in,
                              void* d_out, int out_size, void* d_ws, size_t ws_size,
                              hipStream_t stream) {
    (void)in_sizes; (void)n_in; (void)out_size; (void)ws_size;
    const int*   x      = (const int*)d_in[0];
    const int*   e2     = (const int*)d_in[2];
    const int*   e3     = (const int*)d_in[3];
    const int*   tgt    = (const int*)d_in[4];
    const float* emb    = (const float*)d_in[5];
    const float* W_root = (const float*)d_in[6];
    const float* W_e2   = (const float*)d_in[7];
    const float* W_e3   = (const float*)d_in[8];
    const float* ln_g   = (const float*)d_in[9];
    const float* ln_b   = (const float*)d_in[10];
    const float* reg_W  = (const float*)d_in[11];
    const float* reg_b  = (const float*)d_in[12];
    const float* rln_g  = (const float*)d_in[13];
    const float* rln_b  = (const float*)d_in[14];
    const float* out_W  = (const float*)d_in[15];
    const float* out_b  = (const float*)d_in[16];
    float* out = (float*)d_out;

    // workspace layout — top 183,837,184 B (round-11..15-proven)
    char* ws = (char*)d_ws;
    float* agg     = (float*)(ws);                    // 102,400,000 B
    int*   counts  = (int*)  (ws);                    // aliases agg (dead until layer 0)
    u16*   hb      = (u16*)  (ws + 102400000);        //  51,200,000
    u16*   Wr      = (u16*)  (ws + 153600000);        //     524,288
    u16*   W2c     = (u16*)  (ws + 154124288);        //   2,097,152
    u16*   W3c     = (u16*)  (ws + 156221440);        //   4,718,592
    int*   sorted2 = (int*)  (ws + 160940032);        //   2,400,000
    int*   sorted3 = (int*)  (ws + 163340032);        //   2,400,000
    int*   rp      = (int*)  (ws + 165740032);        //   2,000,020 -> pad 2,000,128
    int*   aux     = (int*)  (ws + 167740160);        //         320 -> pad 1,024
    int*   csrsrc2 = (int*)  (ws + 167741184);        //   4,800,000 (2s x 2t x E2N)
    int*   csrsrc3 = (int*)  (ws + 172541184);        //   7,200,000 (3s x 3t x E3N)
    float* t0      = (float*)(ws + 179741184);        //   2,048,000
    float* t1      = (float*)(ws + 181789184);        //   2,048,000

    embed_kernel<<<N_NODES / 4, 256, 0, stream>>>(x, emb, hb, N_NODES);
    convert_wt<<<(NLAYER * 256 * 256 + 255) / 256, 256, 0, stream>>>(W_root, Wr, NLAYER * 256 * 256, 256, 256);
    convert_cat<<<(NLAYER * 4 * 65536 + 255) / 256, 256, 0, stream>>>(W_e2, W2c, 2, NLAYER * 4 * 65536);
    convert_cat<<<(NLAYER * 9 * 65536 + 255) / 256, 256, 0, stream>>>(W_e3, W3c, 3, NLAYER * 9 * 65536);

    zero_counts<<<(NSEG * NBINS + 255) / 256, 256, 0, stream>>>(counts);
    hist_kernel<<<(TOTENT + 255) / 256, 256, 0, stream>>>(e2, e3, counts);
    scanA<<<NSEG * NSTRIPE, 1024, 0, stream>>>(counts, aux);
    scanB<<<1, 256, 0, stream>>>(aux);
    scanC<<<NSEG * NSTRIPE, 1024, 0, stream>>>(counts, aux);
    copy_rowptr<<<(NSEG * RPW + 255) / 256, 256, 0, stream>>>(counts, rp);
    scatter_kernel<<<(TOTENT + 255) / 256, 256, 0, stream>>>(e2, e3, counts, sorted2, sorted3);

    for (int s = 0; s < 2; ++s)
        for (int t = 0; t < 2; ++t)
            build_csrsrc<<<(E2N + 255) / 256, 256, 0, stream>>>(
                e2 + (size_t)t * E2N, sorted2 + (size_t)s * E2N,
                csrsrc2 + (size_t)(s * 2 + t) * E2N, E2N);
    for (int s = 0; s < 3; ++s)
        for (int t = 0; t < 3; ++t)
            build_csrsrc<<<(E3N + 255) / 256, 256, 0, stream>>>(
                e3 + (size_t)t * E3N, sorted3 + (size_t)s * E3N,
                csrsrc3 + (size_t)(s * 3 + t) * E3N, E3N);

    const int mgrid = ((N_NODES + 127) / 128) * 2;   // 1564 (root)
    const int fgrid = (N_NODES + 63) / 64;           // 1563 (fused conv)

    for (int l = 0; l < NLAYER; ++l) {
        gemm128<<<mgrid, 256, 0, stream>>>(hb, Wr + (size_t)l * 65536, agg, N_NODES);
        fused_conv<2><<<fgrid, 512, 0, stream>>>(
            hb, csrsrc2, rp, W2c + (size_t)l * 4 * 65536, agg, E2N);
        fused_conv<3><<<fgrid, 512, 0, stream>>>(
            hb, csrsrc3, rp + 2 * RPW, W3c + (size_t)l * 9 * 65536, agg, E3N);
        relu_ln_kernel<<<N_NODES / 4, 256, 0, stream>>>(agg, ln_g + l * D, ln_b + l * D, hb, N_NODES);
    }

    head_layer<<<TGT, 256, 0, stream>>>(hb, tgt, nullptr, reg_W, reg_b, rln_g, rln_b, t0, 1);
    head_layer<<<TGT, 256, 0, stream>>>(nullptr, nullptr, t0, reg_W + 65536, reg_b + 256, rln_g + 256, rln_b + 256, t1, 0);
    head_out<<<(TGT + 3) / 4, 256, 0, stream>>>(t1, out_W, out_b, out, TGT);
}

// Round 17
// 2900.427 us; speedup vs baseline: 4.2125x; 1.1600x over previous
//
#include <hip/hip_runtime.h>

typedef unsigned short u16;
typedef __bf16 bf16x8 __attribute__((ext_vector_type(8)));
typedef float f32x4 __attribute__((ext_vector_type(4)));

#define N_NODES 100000
#define D 256
#define NLAYER 4
#define E2N 300000
#define E3N 200000
#define TGT 2000

__device__ __forceinline__ u16 f2b(float f) {
    union { float f; unsigned u; } v; v.f = f;
    unsigned r = v.u + 0x7FFFu + ((v.u >> 16) & 1u);
    return (u16)(r >> 16);
}
__device__ __forceinline__ float b2f(u16 u) {
    union { unsigned u; float f; } v; v.u = ((unsigned)u) << 16; return v.f;
}

// ---------------- embedding gather ----------------
__global__ __launch_bounds__(256)
void embed_kernel(const int* __restrict__ x, const float* __restrict__ emb,
                  u16* __restrict__ hb, int n) {
    int wid = threadIdx.x >> 6, lane = threadIdx.x & 63;
    int row = blockIdx.x * 4 + wid;
    if (row >= n) return;
    int v = x[row];
    float4 f = *(const float4*)(emb + v * D + lane * 4);
    ushort4 o; o.x = f2b(f.x); o.y = f2b(f.y); o.z = f2b(f.z); o.w = f2b(f.w);
    *(ushort4*)(hb + row * D + lane * 4) = o;
}

// ---------------- W_root (L,K,N) f32 -> Wr (L,N,K) bf16 ----------------
__global__ __launch_bounds__(256)
void convert_wt(const float* __restrict__ W, u16* __restrict__ Wt,
                int total, int K, int N) {
    int idx = blockIdx.x * 256 + threadIdx.x;
    if (idx >= total) return;
    int kk = idx % K;
    int rem = idx / K;
    int nn = rem % N;
    int l  = rem / N;
    Wt[idx] = f2b(W[(l * K + kk) * N + nn]);
}

// ---------------- W_eA (L, A*256, A*256) -> Wcat[((l*A+s)*A+t)][c][k] ----------------
__global__ __launch_bounds__(256)
void convert_cat(const float* __restrict__ W, u16* __restrict__ Wt,
                 int A, int total) {
    int idx = blockIdx.x * 256 + threadIdx.x;
    if (idx >= total) return;
    int k = idx & 255;
    int c = (idx >> 8) & 255;
    int r = idx >> 16;           // (l*A + s)*A + t
    int t = r % A; int ls = r / A; int s = ls % A; int l = ls / A;
    int AD = A * 256;
    Wt[idx] = f2b(W[(size_t)(l * AD + t * 256 + k) * AD + s * 256 + c]);
}

// ---------------- counting sort: CSR (rowptr + edge-id col array) per (type,slot) ------
#define NBINS 100000
#define NSEG 5
#define TOTENT 1200000
#define RPW (NBINS + 1)
#define NSTRIPE 16
#define SBINS (NBINS / NSTRIPE)      // 6250
#define BPT 7

__global__ __launch_bounds__(256)
void zero_counts(int* __restrict__ counts) {
    int i = blockIdx.x * 256 + threadIdx.x;
    if (i < NSEG * NBINS) counts[i] = 0;
}

__device__ __forceinline__ void decode_entry(int i, const int* e2, const int* e3,
                                             int& seg, int& key, int& e, int& is2) {
    if (i < 2 * E2N) {
        int s = i / E2N; e = i - s * E2N;
        seg = s; key = e2[s * E2N + e]; is2 = 1;
    } else {
        int j = i - 2 * E2N; int s = j / E3N; e = j - s * E3N;
        seg = 2 + s; key = e3[s * E3N + e]; is2 = 0;
    }
}

__global__ __launch_bounds__(256)
void hist_kernel(const int* __restrict__ e2, const int* __restrict__ e3,
                 int* __restrict__ counts) {
    int i = blockIdx.x * 256 + threadIdx.x;
    if (i >= TOTENT) return;
    int seg, key, e, is2;
    decode_entry(i, e2, e3, seg, key, e, is2);
    atomicAdd(counts + seg * NBINS + key, 1);
}

__global__ __launch_bounds__(1024)
void scanA(int* __restrict__ counts, int* __restrict__ aux) {
    __shared__ int ps[1024];
    int* base = counts + (blockIdx.x / NSTRIPE) * NBINS + (blockIdx.x % NSTRIPE) * SBINS;
    int t = threadIdx.x;
    int b = t * BPT, en = b + BPT; if (en > SBINS) en = SBINS; if (b > SBINS) b = SBINS;
    int s = 0;
    for (int i = b; i < en; ++i) s += base[i];
    ps[t] = s; __syncthreads();
    for (int off = 1; off < 1024; off <<= 1) {
        int v = ps[t];
        if (t >= off) v += ps[t - off];
        __syncthreads();
        ps[t] = v; __syncthreads();
    }
    int run = (t == 0) ? 0 : ps[t - 1];
    for (int i = b; i < en; ++i) { int c = base[i]; base[i] = run; run += c; }
    if (t == 1023) aux[blockIdx.x] = ps[1023];
}

__global__ __launch_bounds__(256)
void scanB(int* __restrict__ aux) {
    int seg = threadIdx.x;
    if (seg >= NSEG) return;
    int run = 0;
    for (int i = 0; i < NSTRIPE; ++i) {
        int c = aux[seg * NSTRIPE + i];
        aux[seg * NSTRIPE + i] = run; run += c;
    }
}

__global__ __launch_bounds__(1024)
void scanC(int* __restrict__ counts, const int* __restrict__ aux) {
    int off = aux[blockIdx.x];
    if (off == 0) return;
    int* base = counts + (blockIdx.x / NSTRIPE) * NBINS + (blockIdx.x % NSTRIPE) * SBINS;
    int t = threadIdx.x;
    int b = t * BPT, en = b + BPT; if (en > SBINS) en = SBINS; if (b > SBINS) b = SBINS;
    for (int i = b; i < en; ++i) base[i] += off;
}

__global__ __launch_bounds__(256)
void copy_rowptr(const int* __restrict__ counts, int* __restrict__ rp) {
    int i = blockIdx.x * 256 + threadIdx.x;
    if (i >= NSEG * RPW) return;
    int seg = i / RPW, k = i - seg * RPW;
    rp[i] = (k < NBINS) ? counts[seg * NBINS + k] : (seg < 2 ? E2N : E3N);
}

__global__ __launch_bounds__(256)
void scatter_kernel(const int* __restrict__ e2, const int* __restrict__ e3,
                    int* __restrict__ counts, int* __restrict__ sorted2,
                    int* __restrict__ sorted3) {
    int i = blockIdx.x * 256 + threadIdx.x;
    if (i >= TOTENT) return;
    int seg, key, e, is2;
    decode_entry(i, e2, e3, seg, key, e, is2);
    int pos = atomicAdd(counts + seg * NBINS + key, 1);
    if (is2) sorted2[seg * E2N + pos] = e;
    else     sorted3[(seg - 2) * E3N + pos] = e;
}

// ---------------- csrsrc[e] = src_ids[csr[e]] ----------------
__global__ __launch_bounds__(256)
void build_csrsrc(const int* __restrict__ src_ids, const int* __restrict__ csr,
                  int* __restrict__ out, int E) {
    int i = blockIdx.x * 256 + threadIdx.x;
    if (i >= E) return;
    out[i] = src_ids[csr[i]];
}

// ---------------- fused LAYER: root + all e2/e3 phases + relu + LN, in-register -------
// Block = 64 dst nodes x 256 cols, 8 waves, 512 threads. 14 phases:
//   ph0: root (A = hin rows, B = Wr)         [diag path, dgf = 1]
//   ph1-4: e2 (s,t); ph5-13: e3 (s,t).  t==s: A row = deg_s * h[node] (no gather).
//   t!=s: round-16 batched gather (index preload + 8 loads in flight).
// acc[4][2] f32 accumulates ALL phases; epilogue does relu + LayerNorm in-block
// (rows are block-exclusive) and writes bf16 hout. agg buffer eliminated.
#define AP 264            // sA pitch in u16

__global__ __launch_bounds__(512, 6)
void fused_layer(const u16* __restrict__ hin, u16* __restrict__ hout,
                 const int* __restrict__ csrsrc2, const int* __restrict__ csrsrc3,
                 const int* __restrict__ rp,
                 const u16* __restrict__ Wr_l, const u16* __restrict__ W2_l,
                 const u16* __restrict__ W3_l,
                 const float* __restrict__ lng, const float* __restrict__ lnb) {
    __shared__ __align__(16) u16 sA[64 * AP];    // 33,792 B
    __shared__ float lnS[64][8];                 //  2,048 B
    __shared__ float lnS2[64][8];                //  2,048 B
    const int m0 = blockIdx.x * 64;
    const int tid = threadIdx.x;
    const int lane = tid & 63;
    const int wid = tid >> 6;          // 0..7
    const int wcol = wid * 32;
    const int node0 = m0 + wid * 8;

    f32x4 acc[4][2];
#pragma unroll
    for (int i = 0; i < 4; ++i)
#pragma unroll
        for (int j = 0; j < 2; ++j)
            acc[i][j] = f32x4{0.f, 0.f, 0.f, 0.f};

#pragma unroll 1
    for (int ph = 0; ph < 14; ++ph) {
        int type, s, t;
        if (ph == 0)      { type = 0; s = 0; t = 0; }
        else if (ph <= 4) { int p = ph - 1; type = 2; s = p >> 1; t = p & 1; }
        else              { int p = ph - 5; type = 3; s = p / 3; t = p - (p / 3) * 3; }

        const int* rps = nullptr;
        const int* cs  = nullptr;
        const u16* Bt;
        int E = 0;
        if (type == 0) {
            Bt = Wr_l;
        } else if (type == 2) {
            rps = rp + s * RPW; E = E2N;
            cs = csrsrc2 + (size_t)(s * 2 + t) * E2N;
            Bt = W2_l + (size_t)(s * 2 + t) * 65536;
        } else {
            rps = rp + (2 + s) * RPW; E = E3N;
            cs = csrsrc3 + (size_t)(s * 3 + t) * E3N;
            Bt = W3_l + (size_t)(s * 3 + t) * 65536;
        }

        // lane-parallel rowptr fetch for this segment
        int rv = 0, ebase = 0, nE = 0;
        if (type != 0) {
            int nidx = node0 + lane;
            nidx = (nidx > N_NODES) ? N_NODES : nidx;
            rv = (lane <= 8) ? rps[nidx] : 0;
            ebase = __shfl(rv, 0);
            nE = __shfl(rv, 8) - ebase;
        }

        __syncthreads();   // previous phase's MFMA done reading sA
        if (type == 0 || t == s) {
            // diag-like staging: A row = dgf * h[node], coalesced
#pragma unroll 1
            for (int r = 0; r < 8; ++r) {
                int nl = wid * 8 + r;
                int node = m0 + nl;
                ushort4 o = {0, 0, 0, 0};
                if (node < N_NODES) {
                    float dgf = (type == 0) ? 1.f
                              : (float)(__shfl(rv, r + 1) - __shfl(rv, r));
                    ushort4 h = *(const ushort4*)(hin + (size_t)node * 256 + lane * 4);
                    o.x = f2b(dgf * b2f(h.x)); o.y = f2b(dgf * b2f(h.y));
                    o.z = f2b(dgf * b2f(h.z)); o.w = f2b(dgf * b2f(h.w));
                }
                *(ushort4*)(sA + nl * AP + lane * 4) = o;
            }
        } else {
            // batched gather: preload indices, 8 row loads in flight
            int myi0 = (lane < nE) ? cs[ebase + lane] : 0;
            int myi1 = (lane + 64 < nE) ? cs[ebase + 64 + lane] : 0;

            int currow = 0;
            int rowend = __shfl(rv, 1) - ebase;
            float4 run = {0.f, 0.f, 0.f, 0.f};
#pragma unroll 1
            for (int eb = 0; eb < nE; eb += 8) {
                ushort4 hv[8];
#pragma unroll
                for (int j = 0; j < 8; ++j) {
                    int e = eb + j;
                    int src;
                    if (e >= nE)      src = 0;
                    else if (e < 64)  src = __shfl(myi0, e);
                    else if (e < 128) src = __shfl(myi1, e - 64);
                    else              src = cs[ebase + e];
                    hv[j] = *(const ushort4*)(hin + (size_t)src * 256 + lane * 4);
                }
#pragma unroll
                for (int j = 0; j < 8; ++j) {
                    int e = eb + j;
                    if (e < nE) {
                        while (e >= rowend) {
                            ushort4 o;
                            o.x = f2b(run.x); o.y = f2b(run.y);
                            o.z = f2b(run.z); o.w = f2b(run.w);
                            *(ushort4*)(sA + (wid * 8 + currow) * AP + lane * 4) = o;
                            run = float4{0.f, 0.f, 0.f, 0.f};
                            ++currow;
                            rowend = __shfl(rv, currow + 1) - ebase;
                        }
                        run.x += b2f(hv[j].x); run.y += b2f(hv[j].y);
                        run.z += b2f(hv[j].z); run.w += b2f(hv[j].w);
                    }
                }
            }
            while (currow < 8) {
                ushort4 o;
                o.x = f2b(run.x); o.y = f2b(run.y);
                o.z = f2b(run.z); o.w = f2b(run.w);
                *(ushort4*)(sA + (wid * 8 + currow) * AP + lane * 4) = o;
                run = float4{0.f, 0.f, 0.f, 0.f};
                ++currow;
            }
        }
        __syncthreads();   // sA ready
        // ---- MFMA: A from LDS, B cols wcol..wcol+31 from global (L2) ----
#pragma unroll
        for (int k0 = 0; k0 < 256; k0 += 64) {
#pragma unroll
            for (int ks = 0; ks < 2; ++ks) {
                const int koff = k0 + ks * 32 + (lane >> 4) * 8;
                bf16x8 af[4], bf[2];
#pragma unroll
                for (int mi = 0; mi < 4; ++mi)
                    af[mi] = *(const bf16x8*)(sA + (mi * 16 + (lane & 15)) * AP + koff);
#pragma unroll
                for (int ni = 0; ni < 2; ++ni)
                    bf[ni] = *(const bf16x8*)(Bt + (size_t)(wcol + ni * 16 + (lane & 15)) * 256 + koff);
#pragma unroll
                for (int mi = 0; mi < 4; ++mi)
#pragma unroll
                    for (int ni = 0; ni < 2; ++ni)
                        acc[mi][ni] = __builtin_amdgcn_mfma_f32_16x16x32_bf16(
                            af[mi], bf[ni], acc[mi][ni], 0, 0, 0);
            }
        }
    }

    // ---- epilogue: relu + LayerNorm (in-block) + bf16 write to hout ----
#pragma unroll
    for (int mi = 0; mi < 4; ++mi)
#pragma unroll
        for (int ni = 0; ni < 2; ++ni)
#pragma unroll
            for (int r = 0; r < 4; ++r)
                acc[mi][ni][r] = fmaxf(acc[mi][ni][r], 0.f);

    const int q = lane >> 4;
#pragma unroll
    for (int mi = 0; mi < 4; ++mi) {
#pragma unroll
        for (int r = 0; r < 4; ++r) {
            float p1 = acc[mi][0][r] + acc[mi][1][r];
            float p2 = acc[mi][0][r] * acc[mi][0][r] + acc[mi][1][r] * acc[mi][1][r];
#pragma unroll
            for (int off = 1; off < 16; off <<= 1) {
                p1 += __shfl_xor(p1, off);
                p2 += __shfl_xor(p2, off);
            }
            if ((lane & 15) == 0) {
                int rl = mi * 16 + q * 4 + r;
                lnS[rl][wid] = p1; lnS2[rl][wid] = p2;
            }
        }
    }
    __syncthreads();
    const float g0 = lng[wcol + (lane & 15)];
    const float g1 = lng[wcol + 16 + (lane & 15)];
    const float b0 = lnb[wcol + (lane & 15)];
    const float b1 = lnb[wcol + 16 + (lane & 15)];
#pragma unroll
    for (int mi = 0; mi < 4; ++mi) {
#pragma unroll
        for (int r = 0; r < 4; ++r) {
            int rl = mi * 16 + q * 4 + r;
            float s1 = 0.f, s2 = 0.f;
#pragma unroll
            for (int w = 0; w < 8; ++w) { s1 += lnS[rl][w]; s2 += lnS2[rl][w]; }
            float mu = s1 * 0.00390625f;
            float var = s2 * 0.00390625f - mu * mu;
            float rs = rsqrtf(var + 1e-5f);
            float y0 = (acc[mi][0][r] - mu) * rs * g0 + b0;
            float y1 = (acc[mi][1][r] - mu) * rs * g1 + b1;
            sA[rl * AP + wcol + (lane & 15)]      = f2b(y0);
            sA[rl * AP + wcol + 16 + (lane & 15)] = f2b(y1);
        }
    }
    __syncthreads();
    {
        int row = tid >> 3;            // 64 rows, 8 threads/row
        int node = m0 + row;
        if (node < N_NODES) {
            int c0 = (tid & 7) * 32;
#pragma unroll
            for (int j = 0; j < 4; ++j)
                *(uint4*)(hout + (size_t)node * 256 + c0 + j * 8) =
                    *(const uint4*)(sA + row * AP + c0 + j * 8);
        }
    }
}

// ---------------- head layers ----------------
__global__ __launch_bounds__(256)
void head_layer(const u16* __restrict__ hb, const int* __restrict__ tgt,
                const float* __restrict__ inf,
                const float* __restrict__ W, const float* __restrict__ bias,
                const float* __restrict__ g, const float* __restrict__ beta,
                float* __restrict__ out, int gather) {
    __shared__ float xr[256];
    __shared__ float sm1[4], sm2[4];
    int t = blockIdx.x, tid = threadIdx.x;
    if (gather) { int node = tgt[t]; xr[tid] = b2f(hb[node * D + tid]); }
    else        { xr[tid] = inf[t * D + tid]; }
    __syncthreads();
    float a = bias[tid];
#pragma unroll 8
    for (int k = 0; k < 256; ++k) a = fmaf(xr[k], W[k * 256 + tid], a);
    float s = a, s2 = a * a;
#pragma unroll
    for (int off = 1; off < 64; off <<= 1) {
        s  += __shfl_xor(s, off);
        s2 += __shfl_xor(s2, off);
    }
    int wid = tid >> 6, lane = tid & 63;
    if (lane == 0) { sm1[wid] = s; sm2[wid] = s2; }
    __syncthreads();
    s  = sm1[0] + sm1[1] + sm1[2] + sm1[3];
    s2 = sm2[0] + sm2[1] + sm2[2] + sm2[3];
    float mu = s * 0.00390625f;
    float var = s2 * 0.00390625f - mu * mu;
    float rs = rsqrtf(var + 1e-5f);
    float y = (a - mu) * rs * g[tid] + beta[tid];
    out[t * 256 + tid] = fmaxf(y, 0.f);
}

__global__ __launch_bounds__(256)
void head_out(const float* __restrict__ in, const float* __restrict__ ow,
              const float* __restrict__ ob, float* __restrict__ out, int T) {
    int wid = threadIdx.x >> 6, lane = threadIdx.x & 63;
    int t = blockIdx.x * 4 + wid;
    if (t >= T) return;
    float4 v = *(const float4*)(in + t * D + lane * 4);
    float4 w = *(const float4*)(ow + lane * 4);
    float s = v.x * w.x + v.y * w.y + v.z * w.z + v.w * w.w;
#pragma unroll
    for (int off = 1; off < 64; off <<= 1) s += __shfl_xor(s, off);
    if (lane == 0) out[t] = s + ob[0];
}

extern "C" void kernel_launch(void* const* d_in, const int* in_sizes, int n_in,
                              void* d_out, int out_size, void* d_ws, size_t ws_size,
                              hipStream_t stream) {
    (void)in_sizes; (void)n_in; (void)out_size; (void)ws_size;
    const int*   x      = (const int*)d_in[0];
    const int*   e2     = (const int*)d_in[2];
    const int*   e3     = (const int*)d_in[3];
    const int*   tgt    = (const int*)d_in[4];
    const float* emb    = (const float*)d_in[5];
    const float* W_root = (const float*)d_in[6];
    const float* W_e2   = (const float*)d_in[7];
    const float* W_e3   = (const float*)d_in[8];
    const float* ln_g   = (const float*)d_in[9];
    const float* ln_b   = (const float*)d_in[10];
    const float* reg_W  = (const float*)d_in[11];
    const float* reg_b  = (const float*)d_in[12];
    const float* rln_g  = (const float*)d_in[13];
    const float* rln_b  = (const float*)d_in[14];
    const float* out_W  = (const float*)d_in[15];
    const float* out_b  = (const float*)d_in[16];
    float* out = (float*)d_out;

    // workspace layout — top 183,837,184 B (round-11..16-proven offsets)
    // agg region (ws+0) repurposed: counts during setup, hb1 during layers.
    char* ws = (char*)d_ws;
    int*   counts  = (int*)  (ws);                    // setup only (2 MB)
    u16*   hb1     = (u16*)  (ws);                    // layers (51.2 MB)
    u16*   hb0     = (u16*)  (ws + 102400000);        //  51,200,000 (embed target)
    u16*   Wr      = (u16*)  (ws + 153600000);        //     524,288
    u16*   W2c     = (u16*)  (ws + 154124288);        //   2,097,152
    u16*   W3c     = (u16*)  (ws + 156221440);        //   4,718,592
    int*   sorted2 = (int*)  (ws + 160940032);        //   2,400,000
    int*   sorted3 = (int*)  (ws + 163340032);        //   2,400,000
    int*   rp      = (int*)  (ws + 165740032);        //   2,000,020 -> pad 2,000,128
    int*   aux     = (int*)  (ws + 167740160);        //         320 -> pad 1,024
    int*   csrsrc2 = (int*)  (ws + 167741184);        //   4,800,000 (2s x 2t x E2N)
    int*   csrsrc3 = (int*)  (ws + 172541184);        //   7,200,000 (3s x 3t x E3N)
    float* t0      = (float*)(ws + 179741184);        //   2,048,000
    float* t1      = (float*)(ws + 181789184);        //   2,048,000

    embed_kernel<<<N_NODES / 4, 256, 0, stream>>>(x, emb, hb0, N_NODES);
    convert_wt<<<(NLAYER * 256 * 256 + 255) / 256, 256, 0, stream>>>(W_root, Wr, NLAYER * 256 * 256, 256, 256);
    convert_cat<<<(NLAYER * 4 * 65536 + 255) / 256, 256, 0, stream>>>(W_e2, W2c, 2, NLAYER * 4 * 65536);
    convert_cat<<<(NLAYER * 9 * 65536 + 255) / 256, 256, 0, stream>>>(W_e3, W3c, 3, NLAYER * 9 * 65536);

    zero_counts<<<(NSEG * NBINS + 255) / 256, 256, 0, stream>>>(counts);
    hist_kernel<<<(TOTENT + 255) / 256, 256, 0, stream>>>(e2, e3, counts);
    scanA<<<NSEG * NSTRIPE, 1024, 0, stream>>>(counts, aux);
    scanB<<<1, 256, 0, stream>>>(aux);
    scanC<<<NSEG * NSTRIPE, 1024, 0, stream>>>(counts, aux);
    copy_rowptr<<<(NSEG * RPW + 255) / 256, 256, 0, stream>>>(counts, rp);
    scatter_kernel<<<(TOTENT + 255) / 256, 256, 0, stream>>>(e2, e3, counts, sorted2, sorted3);

    for (int s = 0; s < 2; ++s)
        for (int t = 0; t < 2; ++t)
            build_csrsrc<<<(E2N + 255) / 256, 256, 0, stream>>>(
                e2 + (size_t)t * E2N, sorted2 + (size_t)s * E2N,
                csrsrc2 + (size_t)(s * 2 + t) * E2N, E2N);
    for (int s = 0; s < 3; ++s)
        for (int t = 0; t < 3; ++t)
            build_csrsrc<<<(E3N + 255) / 256, 256, 0, stream>>>(
                e3 + (size_t)t * E3N, sorted3 + (size_t)s * E3N,
                csrsrc3 + (size_t)(s * 3 + t) * E3N, E3N);

    const int fgrid = (N_NODES + 63) / 64;           // 1563
    u16* hbuf[2] = { hb0, hb1 };
    for (int l = 0; l < NLAYER; ++l) {
        u16* hin  = hbuf[l & 1];         // l0: hb0->hb1, l1: hb1->hb0, ...
        u16* hout = hbuf[(l & 1) ^ 1];
        fused_layer<<<fgrid, 512, 0, stream>>>(
            hin, hout, csrsrc2, csrsrc3, rp,
            Wr  + (size_t)l * 65536,
            W2c + (size_t)l * 4 * 65536,
            W3c + (size_t)l * 9 * 65536,
            ln_g + l * D, ln_b + l * D);
    }
    // NLAYER=4 (even) -> final activations in hb0

    head_layer<<<TGT, 256, 0, stream>>>(hb0, tgt, nullptr, reg_W, reg_b, rln_g, rln_b, t0, 1);
    head_layer<<<TGT, 256, 0, stream>>>(nullptr, nullptr, t0, reg_W + 65536, reg_b + 256, rln_g + 256, rln_b + 256, t1, 0);
    head_out<<<(TGT + 3) / 4, 256, 0, stream>>>(t1, out_W, out_b, out, TGT);
}